// Round 2
// baseline (8345.555 us; speedup 1.0000x reference)
//
#include <hip/hip_runtime.h>
#include <cstdint>
#include <cstddef>

// Problem constants
#define NROWS 32768
#define CIN 256
#define CHID 64
#define KCB 2048
#define NSAMP 10

constexpr uint32_t NKu   = 67108864u;   // NROWS*KCB
constexpr uint32_t HALFu = 335544320u;  // 5*NKu (counter offset for second word's draw)

// ---------------- threefry2x32 (key = jax.random.key(42) -> (0,42)) ----------------
__device__ __forceinline__ void tf2x32(uint32_t x0, uint32_t x1,
                                       uint32_t& o0, uint32_t& o1) {
  constexpr uint32_t K0c = 0u, K1c = 42u;
  constexpr uint32_t K2c = 0x1BD11BDAu ^ K0c ^ K1c;
  const uint32_t ks[3] = {K0c, K1c, K2c};
  x0 += K0c; x1 += K1c;
#pragma unroll
  for (int g = 0; g < 5; ++g) {
    const int R0 = (g & 1) ? 17 : 13;
    const int R1 = (g & 1) ? 29 : 15;
    const int R2 = (g & 1) ? 16 : 26;
    const int R3 = (g & 1) ? 24 : 6;
    x0 += x1; x1 = (x1 << R0) | (x1 >> (32 - R0)); x1 ^= x0;
    x0 += x1; x1 = (x1 << R1) | (x1 >> (32 - R1)); x1 ^= x0;
    x0 += x1; x1 = (x1 << R2) | (x1 >> (32 - R2)); x1 ^= x0;
    x0 += x1; x1 = (x1 << R3) | (x1 >> (32 - R3)); x1 ^= x0;
    x0 += ks[(g + 1) % 3];
    x1 += ks[(g + 2) % 3] + (uint32_t)(g + 1);
  }
  o0 = x0; o1 = x1;
}

__device__ __forceinline__ float gumbel_from_bits(uint32_t bits) {
  float f  = __uint_as_float((bits >> 9) | 0x3f800000u);  // [1,2)
  float u1 = f - 1.0f;                                    // [0,1)
  float u  = fmaxf(u1, 1.17549435e-38f);
  return -__logf(-__logf(u));
}

// ---------------- PHM weights (transposed layouts only) ----------------
// wdT[c*64 + r]  = W_down[r][c]   (r<64 out, c<256 in)
// wuT[k*256 + c] = W_up[c][k]     (c<256 out, k<64 in)
__global__ void __launch_bounds__(256) k_weights(
    const float* __restrict__ ad, const float* __restrict__ sd,
    const float* __restrict__ au, const float* __restrict__ su,
    float* __restrict__ wdT, float* __restrict__ wuT) {
  int gid = blockIdx.x * 256 + threadIdx.x;
  if (gid < CHID * CIN) {            // W_down [64][256]
    int r = gid >> 8, c = gid & 255;
    int i = r >> 4, kq = r & 15, j = c >> 6, l = c & 63;
    float acc = 0.f;
#pragma unroll
    for (int n = 0; n < 4; ++n)
      acc = fmaf(ad[n * 16 + i * 4 + j], sd[n * 1024 + kq * 64 + l], acc);
    wdT[c * CHID + r] = acc;
  } else {                           // W_up [256][64]
    int g2 = gid - CHID * CIN;
    int r = g2 >> 6, c = g2 & 63;
    int i = r >> 6, kq = r & 63, j = c >> 4, l = c & 15;
    float acc = 0.f;
#pragma unroll
    for (int n = 0; n < 4; ++n)
      acc = fmaf(au[n * 16 + i * 4 + j], su[n * 1024 + kq * 16 + l], acc);
    wuT[c * CIN + r] = acc;
  }
}

// codebook row norms
__global__ void k_cbnorm(const float* __restrict__ cb, float* __restrict__ cb2) {
  int k = blockIdx.x * blockDim.x + threadIdx.x;
  if (k >= KCB) return;
  const float4* row = (const float4*)(cb + (size_t)k * CIN);
  float acc = 0.f;
  for (int c4 = 0; c4 < CIN / 4; ++c4) {
    float4 v = row[c4];
    acc += v.x * v.x; acc += v.y * v.y; acc += v.z * v.z; acc += v.w * v.w;
  }
  cb2[k] = acc;
}

// Fused PHM: pc[i] = relu(ge[i] @ Wd^T + bd) @ Wu^T + bu   (one block per row)
__global__ void __launch_bounds__(256) k_pcf(
    const float* __restrict__ ge, const float* __restrict__ wdT,
    const float* __restrict__ bd, const float* __restrict__ wuT,
    const float* __restrict__ bu, float* __restrict__ pc) {
  __shared__ float ges[256];
  __shared__ float hp[4][64];
  __shared__ float hs[64];
  int i = blockIdx.x, tid = threadIdx.x;
  ges[tid] = ge[(size_t)i * CIN + tid];
  __syncthreads();
  int r = tid & 63, q = tid >> 6;
  float a = 0.f;
#pragma unroll
  for (int c = 0; c < 64; ++c)
    a = fmaf(ges[q * 64 + c], wdT[(q * 64 + c) * CHID + r], a);
  hp[q][r] = a;
  __syncthreads();
  if (tid < 64) {
    float v = hp[0][tid] + hp[1][tid] + hp[2][tid] + hp[3][tid] + bd[tid];
    hs[tid] = fmaxf(v, 0.f);
  }
  __syncthreads();
  float acc = bu[tid];
#pragma unroll
  for (int kq = 0; kq < CHID; ++kq)
    acc = fmaf(hs[kq], wuT[kq * CIN + tid], acc);
  pc[(size_t)i * CIN + tid] = acc;
}

// Fused distance + Gumbel-argmax sampling. Block = 16 rows x 16 k-lanes.
// Per-row-constant terms dropped: score_k = 2*dot(pc_i, cb_k) - ||cb_k||^2.
__global__ void __launch_bounds__(256) k_sample(
    const float* __restrict__ pc, const float* __restrict__ cb,
    const float* __restrict__ cb2, int* __restrict__ draws) {
  __shared__ float pcs[16][260];   // padded: rows 16B-aligned, banks spread
  int tid = threadIdx.x;
  int i0 = blockIdx.x * 16;
  for (int idx = tid; idx < 16 * 256; idx += 256) {
    int r = idx >> 8, c = idx & 255;
    pcs[r][c] = pc[(size_t)(i0 + r) * CIN + c];
  }
  __syncthreads();
  int row = tid >> 4, klane = tid & 15;
  int i = i0 + row;
  const float4* pr4 = (const float4*)&pcs[row][0];
  float best[10]; int bi[10];
#pragma unroll
  for (int s = 0; s < 10; ++s) { best[s] = -3.0e38f; bi[s] = 0; }
  uint32_t ibase = (uint32_t)i * (uint32_t)KCB;
  for (int j = 0; j < 128; ++j) {
    int k = klane + (j << 4);
    const float4* crow = (const float4*)(cb + (size_t)k * CIN);
    float acc = 0.f;
#pragma unroll 16
    for (int c4 = 0; c4 < 64; ++c4) {
      float4 a = pr4[c4];
      float4 b = crow[c4];
      acc = fmaf(a.x, b.x, acc);
      acc = fmaf(a.y, b.y, acc);
      acc = fmaf(a.z, b.z, acc);
      acc = fmaf(a.w, b.w, acc);
    }
    float logit = 2.0f * acc - cb2[k];
    uint32_t kb = ibase + (uint32_t)k;
#pragma unroll
    for (int sp5 = 0; sp5 < 5; ++sp5) {
      uint32_t blk = (uint32_t)sp5 * NKu + kb;
      uint32_t o0, o1;
      tf2x32(blk, blk + HALFu, o0, o1);
      float v0 = gumbel_from_bits(o0) + logit;
      float v1 = gumbel_from_bits(o1) + logit;
      if (v0 > best[sp5])     { best[sp5] = v0;     bi[sp5] = k; }
      if (v1 > best[sp5 + 5]) { best[sp5 + 5] = v1; bi[sp5 + 5] = k; }
    }
  }
#pragma unroll
  for (int s = 0; s < 10; ++s) {
#pragma unroll
    for (int m = 1; m < 16; m <<= 1) {
      float ob = __shfl_xor(best[s], m, 64);
      int   oi = __shfl_xor(bi[s], m, 64);
      if (ob > best[s] || (ob == best[s] && oi < bi[s])) { best[s] = ob; bi[s] = oi; }
    }
    if (klane == 0) draws[s * NROWS + i] = bi[s];
  }
}

// static sorting network (compile-time indices -> registers)
__device__ __forceinline__ void load_sorted_draws(const int* dl, int* d) {
#pragma unroll
  for (int s = 0; s < NSAMP; ++s) d[s] = dl[s];
#pragma unroll
  for (int p = 0; p < NSAMP - 1; ++p)
#pragma unroll
    for (int a = 0; a < NSAMP - 1 - p; ++a) {
      int lo = min(d[a], d[a + 1]);
      int hi = max(d[a], d[a + 1]);
      d[a] = lo; d[a + 1] = hi;
    }
}

// dw[k][c] += count * pc[i][c]  (atomic fp32 into single 2MB buffer)
__global__ void __launch_bounds__(256) k_dw(const int* __restrict__ draws,
                                            const float* __restrict__ pc,
                                            float* __restrict__ dw) {
  __shared__ int dl[NSAMP];
  int i = blockIdx.x, tid = threadIdx.x;
  if (tid < NSAMP) dl[tid] = draws[tid * NROWS + i];
  __syncthreads();
  int d[NSAMP];
  load_sorted_draws(dl, d);
  float pcv = pc[(size_t)i * CIN + tid];
#pragma unroll
  for (int a = 0; a < NSAMP; ++a) {
    bool first = (a == 0) || (d[a] != d[a - 1]);
    if (first) {
      int c = 1;
#pragma unroll
      for (int b2 = a + 1; b2 < NSAMP; ++b2) c += (d[b2] == d[a]) ? 1 : 0;
      atomicAdd(&dw[(size_t)d[a] * CIN + tid], (float)c * pcv);
    }
  }
}

// out0 = x + (p_c + (p_q - p_c)) + p_emb, in place over the pc buffer; c_loss partials
__global__ void __launch_bounds__(256) k_out0(
    const int* __restrict__ draws, const float* __restrict__ cb,
    float* __restrict__ pc_out0, const float* __restrict__ x,
    const float* __restrict__ pemb, float* __restrict__ closs) {
  __shared__ int dl[NSAMP];
  __shared__ float red[256];
  int i = blockIdx.x, tid = threadIdx.x;
  if (tid < NSAMP) dl[tid] = draws[tid * NROWS + i];
  __syncthreads();
  int d[NSAMP];
  load_sorted_draws(dl, d);
  float acc = 0.f;
#pragma unroll
  for (int a = 0; a < NSAMP; ++a) {
    bool first = (a == 0) || (d[a] != d[a - 1]);
    if (first) {
      int c = 1;
#pragma unroll
      for (int b2 = a + 1; b2 < NSAMP; ++b2) c += (d[b2] == d[a]) ? 1 : 0;
      acc = fmaf((float)c, cb[(size_t)d[a] * CIN + tid], acc);
    }
  }
  float pq  = acc / 10.0f;
  float pcv = pc_out0[(size_t)i * CIN + tid];
  float t   = pq - pcv;
  float pr  = (pcv + t) + pemb[tid];
  pc_out0[(size_t)i * CIN + tid] = x[(size_t)i * CIN + tid] + pr;
  red[tid] = t * t;
  __syncthreads();
  for (int off = 128; off > 0; off >>= 1) {
    if (tid < off) red[tid] += red[tid + off];
    __syncthreads();
  }
  if (tid == 0) atomicAdd(closs, red[0]);
}

__global__ void k_final(const float* __restrict__ closs, float* __restrict__ dst) {
  if (blockIdx.x == 0 && threadIdx.x == 0) dst[0] = closs[0] / 8388608.0f;
}

// per-k draw counts via LDS histogram
__global__ void __launch_bounds__(256) k_hist(const int* __restrict__ draws,
                                              int* __restrict__ counts) {
  __shared__ int hist[KCB];
  for (int b = threadIdx.x; b < KCB; b += 256) hist[b] = 0;
  __syncthreads();
  const int total = NSAMP * NROWS;
  for (int idx = blockIdx.x * 256 + threadIdx.x; idx < total; idx += gridDim.x * 256)
    atomicAdd(&hist[draws[idx]], 1);
  __syncthreads();
  for (int b = threadIdx.x; b < KCB; b += 256)
    if (hist[b]) atomicAdd(&counts[b], hist[b]);
}

// EMA cluster-size update (single block for deterministic n_tot)
__global__ void __launch_bounds__(256) k_ema(
    const int* __restrict__ counts, const float* __restrict__ ecs,
    float* __restrict__ ema_dst, float* __restrict__ ema_ws) {
  __shared__ float e_sh[KCB];
  __shared__ float red[256];
  int tid = threadIdx.x;
  float psum = 0.f;
  for (int k = tid; k < KCB; k += 256) {
    float s10 = (float)counts[k] / 10.0f;
    float e = ecs[k] * 0.9f + 0.1f * s10;
    e_sh[k] = e;
    psum += e;
  }
  red[tid] = psum;
  __syncthreads();
  for (int off = 128; off > 0; off >>= 1) {
    if (tid < off) red[tid] += red[tid + off];
    __syncthreads();
  }
  float ntot = red[0];
  float denom = ntot + 20.48f;   // K * EPS
  for (int k = tid; k < KCB; k += 256) {
    float v = (e_sh[k] + 0.01f) / denom * ntot;
    ema_dst[k] = v;
    ema_ws[k]  = v;
  }
}

// new_codebook = cb*0.9 + 0.1*((dw/10) / ema)
__global__ void k_codebook(const float* __restrict__ dw,
                           const float* __restrict__ cb,
                           const float* __restrict__ ema_ws,
                           float* __restrict__ out_cb) {
  int gid = blockIdx.x * blockDim.x + threadIdx.x;
  if (gid >= KCB * CIN) return;
  int k = gid >> 8;
  float dw10 = dw[gid] / 10.0f;
  float ratio = dw10 / ema_ws[k];
  out_cb[gid] = cb[gid] * 0.9f + 0.1f * ratio;
}

extern "C" void kernel_launch(void* const* d_in, const int* in_sizes, int n_in,
                              void* d_out, int out_size, void* d_ws, size_t ws_size,
                              hipStream_t stream) {
  (void)in_sizes; (void)n_in; (void)out_size; (void)ws_size;
  const float* x    = (const float*)d_in[0];
  const float* ge   = (const float*)d_in[1];
  const float* pemb = (const float*)d_in[2];
  const float* cb   = (const float*)d_in[3];
  const float* ecs  = (const float*)d_in[4];
  const float* ad   = (const float*)d_in[5];
  const float* sd   = (const float*)d_in[6];
  const float* bd   = (const float*)d_in[7];
  const float* au   = (const float*)d_in[8];
  const float* su   = (const float*)d_in[9];
  const float* bu   = (const float*)d_in[10];

  float* out0  = (float*)d_out;                         // [N, CIN]; doubles as pc scratch
  float* outL  = out0 + (size_t)NROWS * CIN;            // scalar c_loss
  float* outCB = outL + 1;                              // [K, CIN]
  float* outE  = outCB + (size_t)KCB * CIN;             // [K]

  // workspace layout (total 3,563,776 B ~= 3.4 MiB)
  char* w = (char*)d_ws;
  float* wdT  = (float*)(w + 0);          //  65,536 B
  float* wuT  = (float*)(w + 65536);      //  65,536 B
  float* cb2  = (float*)(w + 131072);     //   8,192 B
  int*   dr   = (int*)  (w + 139264);     // 1,310,720 B  draws [10][N]
  int*   cnt  = (int*)  (w + 1449984);    //   8,192 B
  float* clo  = (float*)(w + 1458176);    //     256 B
  float* dwa  = (float*)(w + 1458432);    // 2,097,152 B  dw accum [K][CIN]
  float* emaw = (float*)(w + 3555584);    //   8,192 B

  // zero cnt + clo + dw accumulator in one shot (contiguous)
  hipMemsetAsync(cnt, 0, 8192 + 256 + 2097152, stream);

  k_weights<<<128, 256, 0, stream>>>(ad, sd, au, su, wdT, wuT);
  k_cbnorm<<<8, 256, 0, stream>>>(cb, cb2);
  k_pcf<<<NROWS, 256, 0, stream>>>(ge, wdT, bd, wuT, bu, out0);      // pc -> out0 region
  k_sample<<<NROWS / 16, 256, 0, stream>>>(out0, cb, cb2, dr);
  k_dw<<<NROWS, 256, 0, stream>>>(dr, out0, dwa);                    // reads pristine pc
  k_hist<<<64, 256, 0, stream>>>(dr, cnt);
  k_ema<<<1, 256, 0, stream>>>(cnt, ecs, outE, emaw);
  k_out0<<<NROWS, 256, 0, stream>>>(dr, cb, out0, x, pemb, clo);     // in-place transform
  k_final<<<1, 64, 0, stream>>>(clo, outL);
  k_codebook<<<2048, 256, 0, stream>>>(dwa, cb, emaw, outCB);
}

// Round 3
// 2519.156 us; speedup vs baseline: 3.3128x; 3.3128x over previous
//
#include <hip/hip_runtime.h>
#include <cstdint>
#include <cstddef>

// Problem constants
#define NROWS 32768
#define CIN 256
#define CHID 64
#define KCB 2048
#define NSAMP 10

constexpr uint32_t NKu   = 67108864u;   // NROWS*KCB
constexpr uint32_t HALFu = 335544320u;  // 5*NKu (counter offset for second word's draw)

using f32x4 = __attribute__((ext_vector_type(4))) float;
using bf16x8 = __attribute__((ext_vector_type(8))) short;

// ---------------- threefry2x32 (key = jax.random.key(42) -> (0,42)) ----------------
__device__ __forceinline__ void tf2x32(uint32_t x0, uint32_t x1,
                                       uint32_t& o0, uint32_t& o1) {
  constexpr uint32_t K0c = 0u, K1c = 42u;
  constexpr uint32_t K2c = 0x1BD11BDAu ^ K0c ^ K1c;
  const uint32_t ks[3] = {K0c, K1c, K2c};
  x0 += K0c; x1 += K1c;
#pragma unroll
  for (int g = 0; g < 5; ++g) {
    const int R0 = (g & 1) ? 17 : 13;
    const int R1 = (g & 1) ? 29 : 15;
    const int R2 = (g & 1) ? 16 : 26;
    const int R3 = (g & 1) ? 24 : 6;
    x0 += x1; x1 = (x1 << R0) | (x1 >> (32 - R0)); x1 ^= x0;
    x0 += x1; x1 = (x1 << R1) | (x1 >> (32 - R1)); x1 ^= x0;
    x0 += x1; x1 = (x1 << R2) | (x1 >> (32 - R2)); x1 ^= x0;
    x0 += x1; x1 = (x1 << R3) | (x1 >> (32 - R3)); x1 ^= x0;
    x0 += ks[(g + 1) % 3];
    x1 += ks[(g + 2) % 3] + (uint32_t)(g + 1);
  }
  o0 = x0; o1 = x1;
}

__device__ __forceinline__ float gumbel_from_bits(uint32_t bits) {
  float f  = __uint_as_float((bits >> 9) | 0x3f800000u);  // [1,2)
  float u1 = f - 1.0f;                                    // [0,1)
  float u  = fmaxf(u1, 1.17549435e-38f);
  return -__logf(-__logf(u));
}

__device__ __forceinline__ ushort bf16_rne(float x) {
  uint32_t b = __float_as_uint(x);
  return (ushort)((b + 0x7fffu + ((b >> 16) & 1u)) >> 16);
}
__device__ __forceinline__ float bf16_tof(ushort u) {
  return __uint_as_float(((uint32_t)u) << 16);
}

// ---------------- PHM weights (transposed layouts only) ----------------
__global__ void __launch_bounds__(256) k_weights(
    const float* __restrict__ ad, const float* __restrict__ sd,
    const float* __restrict__ au, const float* __restrict__ su,
    float* __restrict__ wdT, float* __restrict__ wuT) {
  int gid = blockIdx.x * 256 + threadIdx.x;
  if (gid < CHID * CIN) {            // W_down [64][256]
    int r = gid >> 8, c = gid & 255;
    int i = r >> 4, kq = r & 15, j = c >> 6, l = c & 63;
    float acc = 0.f;
#pragma unroll
    for (int n = 0; n < 4; ++n)
      acc = fmaf(ad[n * 16 + i * 4 + j], sd[n * 1024 + kq * 64 + l], acc);
    wdT[c * CHID + r] = acc;
  } else {                           // W_up [256][64]
    int g2 = gid - CHID * CIN;
    int r = g2 >> 6, c = g2 & 63;
    int i = r >> 6, kq = r & 63, j = c >> 4, l = c & 15;
    float acc = 0.f;
#pragma unroll
    for (int n = 0; n < 4; ++n)
      acc = fmaf(au[n * 16 + i * 4 + j], su[n * 1024 + kq * 16 + l], acc);
    wuT[c * CIN + r] = acc;
  }
}

// codebook row norms
__global__ void k_cbnorm(const float* __restrict__ cb, float* __restrict__ cb2) {
  int k = blockIdx.x * blockDim.x + threadIdx.x;
  if (k >= KCB) return;
  const float4* row = (const float4*)(cb + (size_t)k * CIN);
  float acc = 0.f;
  for (int c4 = 0; c4 < CIN / 4; ++c4) {
    float4 v = row[c4];
    acc += v.x * v.x; acc += v.y * v.y; acc += v.z * v.z; acc += v.w * v.w;
  }
  cb2[k] = acc;
}

// Fused PHM: pc[i] = relu(ge[i] @ Wd^T + bd) @ Wu^T + bu   (one block per row)
__global__ void __launch_bounds__(256) k_pcf(
    const float* __restrict__ ge, const float* __restrict__ wdT,
    const float* __restrict__ bd, const float* __restrict__ wuT,
    const float* __restrict__ bu, float* __restrict__ pc) {
  __shared__ float ges[256];
  __shared__ float hp[4][64];
  __shared__ float hs[64];
  int i = blockIdx.x, tid = threadIdx.x;
  ges[tid] = ge[(size_t)i * CIN + tid];
  __syncthreads();
  int r = tid & 63, q = tid >> 6;
  float a = 0.f;
#pragma unroll
  for (int c = 0; c < 64; ++c)
    a = fmaf(ges[q * 64 + c], wdT[(q * 64 + c) * CHID + r], a);
  hp[q][r] = a;
  __syncthreads();
  if (tid < 64) {
    float v = hp[0][tid] + hp[1][tid] + hp[2][tid] + hp[3][tid] + bd[tid];
    hs[tid] = fmaxf(v, 0.f);
  }
  __syncthreads();
  float acc = bu[tid];
#pragma unroll
  for (int kq = 0; kq < CHID; ++kq)
    acc = fmaf(hs[kq], wuT[kq * CIN + tid], acc);
  pc[(size_t)i * CIN + tid] = acc;
}

// ---------------- Fused MFMA scores + Gumbel-argmax sampling ----------------
// Block: 32 rows x all K. Per 32-k tile: stage cb hi/lo bf16 in LDS, MFMA
// (hi*hi + lo*hi + hi*lo) for near-fp32 dot, then per-lane threefry gumbel.
// Wave w: i-half = w&1, k-half = w>>1. D layout: col=lane&15 (i), row=4*(lane>>4)+r (k).
__global__ void __launch_bounds__(256) k_sample(
    const float* __restrict__ pc, const float* __restrict__ cb,
    const float* __restrict__ cb2, int* __restrict__ draws) {
  __shared__ __attribute__((aligned(16))) ushort cbs_hi[32][264];
  __shared__ __attribute__((aligned(16))) ushort cbs_lo[32][264];
  __shared__ __attribute__((aligned(16))) ushort pcs_hi[32][264];
  __shared__ __attribute__((aligned(16))) ushort pcs_lo[32][264];
  __shared__ float rbest[4][16][10];
  __shared__ int   rbi[4][16][10];

  int tid = threadIdx.x;
  int w = tid >> 6, lane = tid & 63;
  int ih = w & 1, kh = w >> 1;
  int l15 = lane & 15, lq = lane >> 4;

  // stage pc tile (32 rows) once: hi + residual-lo bf16
  {
    const float* base = pc + (size_t)blockIdx.x * 32 * CIN;
#pragma unroll
    for (int rep = 0; rep < 8; ++rep) {
      int f = rep * 1024 + tid * 4;
      int row = f >> 8, col = f & 255;
      float4 v = *(const float4*)(base + row * CIN + col);
      ushort4 hh, ll;
      hh.x = bf16_rne(v.x); ll.x = bf16_rne(v.x - bf16_tof(hh.x));
      hh.y = bf16_rne(v.y); ll.y = bf16_rne(v.y - bf16_tof(hh.y));
      hh.z = bf16_rne(v.z); ll.z = bf16_rne(v.z - bf16_tof(hh.z));
      hh.w = bf16_rne(v.w); ll.w = bf16_rne(v.w - bf16_tof(hh.w));
      *(ushort4*)&pcs_hi[row][col] = hh;
      *(ushort4*)&pcs_lo[row][col] = ll;
    }
  }

  int i_loc = l15 + 16 * ih;
  int i_abs = blockIdx.x * 32 + i_loc;
  uint32_t ibase = (uint32_t)i_abs * (uint32_t)KCB;
  int krow = 16 * kh + l15;       // A-operand row (cb row within tile)

  float best[10]; int bi[10];
#pragma unroll
  for (int s = 0; s < 10; ++s) { best[s] = -3.0e38f; bi[s] = 0; }

  for (int t = 0; t < 64; ++t) {
    __syncthreads();   // protect previous tile before overwrite (also covers pcs stage)
    {
      const float* base = cb + (size_t)t * 32 * CIN;
#pragma unroll
      for (int rep = 0; rep < 8; ++rep) {
        int f = rep * 1024 + tid * 4;
        int row = f >> 8, col = f & 255;
        float4 v = *(const float4*)(base + row * CIN + col);
        ushort4 hh, ll;
        hh.x = bf16_rne(v.x); ll.x = bf16_rne(v.x - bf16_tof(hh.x));
        hh.y = bf16_rne(v.y); ll.y = bf16_rne(v.y - bf16_tof(hh.y));
        hh.z = bf16_rne(v.z); ll.z = bf16_rne(v.z - bf16_tof(hh.z));
        hh.w = bf16_rne(v.w); ll.w = bf16_rne(v.w - bf16_tof(hh.w));
        *(ushort4*)&cbs_hi[row][col] = hh;
        *(ushort4*)&cbs_lo[row][col] = ll;
      }
    }
    __syncthreads();

    f32x4 acc = {0.f, 0.f, 0.f, 0.f};
#pragma unroll
    for (int ks = 0; ks < 8; ++ks) {
      int kk = ks * 32 + 8 * lq;
      bf16x8 ah = *(const bf16x8*)&cbs_hi[krow][kk];
      bf16x8 al = *(const bf16x8*)&cbs_lo[krow][kk];
      bf16x8 bh = *(const bf16x8*)&pcs_hi[i_loc][kk];
      bf16x8 bl = *(const bf16x8*)&pcs_lo[i_loc][kk];
      acc = __builtin_amdgcn_mfma_f32_16x16x32_bf16(ah, bh, acc, 0, 0, 0);
      acc = __builtin_amdgcn_mfma_f32_16x16x32_bf16(al, bh, acc, 0, 0, 0);
      acc = __builtin_amdgcn_mfma_f32_16x16x32_bf16(ah, bl, acc, 0, 0, 0);
    }

    int k0 = t * 32 + 16 * kh + 4 * lq;
#pragma unroll
    for (int r = 0; r < 4; ++r) {
      int k = k0 + r;
      float score = 2.0f * acc[r] - cb2[k];
      uint32_t kb = ibase + (uint32_t)k;
#pragma unroll
      for (int s5 = 0; s5 < 5; ++s5) {
        uint32_t blk = (uint32_t)s5 * NKu + kb;
        uint32_t o0, o1;
        tf2x32(blk, blk + HALFu, o0, o1);
        float v0 = gumbel_from_bits(o0) + score;
        float v1 = gumbel_from_bits(o1) + score;
        if (v0 > best[s5])     { best[s5] = v0;     bi[s5] = k; }
        if (v1 > best[s5 + 5]) { best[s5 + 5] = v1; bi[s5 + 5] = k; }
      }
    }
  }

  // intra-wave reduce across the 4 k-quad lanes sharing the same i
#pragma unroll
  for (int s = 0; s < 10; ++s) {
#pragma unroll
    for (int m = 16; m < 64; m <<= 1) {
      float ob = __shfl_xor(best[s], m, 64);
      int   oi = __shfl_xor(bi[s], m, 64);
      if (ob > best[s] || (ob == best[s] && oi < bi[s])) { best[s] = ob; bi[s] = oi; }
    }
  }
  if (lane < 16) {
#pragma unroll
    for (int s = 0; s < 10; ++s) { rbest[w][lane][s] = best[s]; rbi[w][lane][s] = bi[s]; }
  }
  __syncthreads();
  // cross-wave merge: waves (0,2) cover i 0-15; waves (1,3) cover i 16-31
  for (int item = tid; item < 320; item += 256) {
    int s = item % 10;
    int i16 = (item / 10) & 15;
    int ihh = item / 160;
    float b0 = rbest[ihh][i16][s], b2 = rbest[ihh + 2][i16][s];
    int j0 = rbi[ihh][i16][s],     j2 = rbi[ihh + 2][i16][s];
    int pick = (b2 > b0 || (b2 == b0 && j2 < j0)) ? j2 : j0;
    draws[s * NROWS + blockIdx.x * 32 + ihh * 16 + i16] = pick;
  }
}

// static sorting network (compile-time indices -> registers)
__device__ __forceinline__ void load_sorted_draws(const int* dl, int* d) {
#pragma unroll
  for (int s = 0; s < NSAMP; ++s) d[s] = dl[s];
#pragma unroll
  for (int p = 0; p < NSAMP - 1; ++p)
#pragma unroll
    for (int a = 0; a < NSAMP - 1 - p; ++a) {
      int lo = min(d[a], d[a + 1]);
      int hi = max(d[a], d[a + 1]);
      d[a] = lo; d[a + 1] = hi;
    }
}

// dw[k][c] += count * pc[i][c]  (atomic fp32)
__global__ void __launch_bounds__(256) k_dw(const int* __restrict__ draws,
                                            const float* __restrict__ pc,
                                            float* __restrict__ dw) {
  __shared__ int dl[NSAMP];
  int i = blockIdx.x, tid = threadIdx.x;
  if (tid < NSAMP) dl[tid] = draws[tid * NROWS + i];
  __syncthreads();
  int d[NSAMP];
  load_sorted_draws(dl, d);
  float pcv = pc[(size_t)i * CIN + tid];
#pragma unroll
  for (int a = 0; a < NSAMP; ++a) {
    bool first = (a == 0) || (d[a] != d[a - 1]);
    if (first) {
      int c = 1;
#pragma unroll
      for (int b2 = a + 1; b2 < NSAMP; ++b2) c += (d[b2] == d[a]) ? 1 : 0;
      atomicAdd(&dw[(size_t)d[a] * CIN + tid], (float)c * pcv);
    }
  }
}

// out0 = x + (p_c + (p_q - p_c)) + p_emb, in place over pc buffer; c_loss partials
__global__ void __launch_bounds__(256) k_out0(
    const int* __restrict__ draws, const float* __restrict__ cb,
    float* __restrict__ pc_out0, const float* __restrict__ x,
    const float* __restrict__ pemb, float* __restrict__ closs) {
  __shared__ int dl[NSAMP];
  __shared__ float red[256];
  int i = blockIdx.x, tid = threadIdx.x;
  if (tid < NSAMP) dl[tid] = draws[tid * NROWS + i];
  __syncthreads();
  int d[NSAMP];
  load_sorted_draws(dl, d);
  float acc = 0.f;
#pragma unroll
  for (int a = 0; a < NSAMP; ++a) {
    bool first = (a == 0) || (d[a] != d[a - 1]);
    if (first) {
      int c = 1;
#pragma unroll
      for (int b2 = a + 1; b2 < NSAMP; ++b2) c += (d[b2] == d[a]) ? 1 : 0;
      acc = fmaf((float)c, cb[(size_t)d[a] * CIN + tid], acc);
    }
  }
  float pq  = acc / 10.0f;
  float pcv = pc_out0[(size_t)i * CIN + tid];
  float t   = pq - pcv;
  float pr  = (pcv + t) + pemb[tid];
  pc_out0[(size_t)i * CIN + tid] = x[(size_t)i * CIN + tid] + pr;
  red[tid] = t * t;
  __syncthreads();
  for (int off = 128; off > 0; off >>= 1) {
    if (tid < off) red[tid] += red[tid + off];
    __syncthreads();
  }
  if (tid == 0) atomicAdd(closs, red[0]);
}

__global__ void k_final(const float* __restrict__ closs, float* __restrict__ dst) {
  if (blockIdx.x == 0 && threadIdx.x == 0) dst[0] = closs[0] / 8388608.0f;
}

// per-k draw counts via LDS histogram
__global__ void __launch_bounds__(256) k_hist(const int* __restrict__ draws,
                                              int* __restrict__ counts) {
  __shared__ int hist[KCB];
  for (int b = threadIdx.x; b < KCB; b += 256) hist[b] = 0;
  __syncthreads();
  const int total = NSAMP * NROWS;
  for (int idx = blockIdx.x * 256 + threadIdx.x; idx < total; idx += gridDim.x * 256)
    atomicAdd(&hist[draws[idx]], 1);
  __syncthreads();
  for (int b = threadIdx.x; b < KCB; b += 256)
    if (hist[b]) atomicAdd(&counts[b], hist[b]);
}

// EMA cluster-size update (single block for deterministic n_tot)
__global__ void __launch_bounds__(256) k_ema(
    const int* __restrict__ counts, const float* __restrict__ ecs,
    float* __restrict__ ema_dst, float* __restrict__ ema_ws) {
  __shared__ float e_sh[KCB];
  __shared__ float red[256];
  int tid = threadIdx.x;
  float psum = 0.f;
  for (int k = tid; k < KCB; k += 256) {
    float s10 = (float)counts[k] / 10.0f;
    float e = ecs[k] * 0.9f + 0.1f * s10;
    e_sh[k] = e;
    psum += e;
  }
  red[tid] = psum;
  __syncthreads();
  for (int off = 128; off > 0; off >>= 1) {
    if (tid < off) red[tid] += red[tid + off];
    __syncthreads();
  }
  float ntot = red[0];
  float denom = ntot + 20.48f;   // K * EPS
  for (int k = tid; k < KCB; k += 256) {
    float v = (e_sh[k] + 0.01f) / denom * ntot;
    ema_dst[k] = v;
    ema_ws[k]  = v;
  }
}

// new_codebook = cb*0.9 + 0.1*((dw/10) / ema)
__global__ void k_codebook(const float* __restrict__ dw,
                           const float* __restrict__ cb,
                           const float* __restrict__ ema_ws,
                           float* __restrict__ out_cb) {
  int gid = blockIdx.x * blockDim.x + threadIdx.x;
  if (gid >= KCB * CIN) return;
  int k = gid >> 8;
  float dw10 = dw[gid] / 10.0f;
  float ratio = dw10 / ema_ws[k];
  out_cb[gid] = cb[gid] * 0.9f + 0.1f * ratio;
}

extern "C" void kernel_launch(void* const* d_in, const int* in_sizes, int n_in,
                              void* d_out, int out_size, void* d_ws, size_t ws_size,
                              hipStream_t stream) {
  (void)in_sizes; (void)n_in; (void)out_size; (void)ws_size;
  const float* x    = (const float*)d_in[0];
  const float* ge   = (const float*)d_in[1];
  const float* pemb = (const float*)d_in[2];
  const float* cb   = (const float*)d_in[3];
  const float* ecs  = (const float*)d_in[4];
  const float* ad   = (const float*)d_in[5];
  const float* sd   = (const float*)d_in[6];
  const float* bd   = (const float*)d_in[7];
  const float* au   = (const float*)d_in[8];
  const float* su   = (const float*)d_in[9];
  const float* bu   = (const float*)d_in[10];

  float* out0  = (float*)d_out;                         // [N, CIN]; doubles as pc scratch
  float* outL  = out0 + (size_t)NROWS * CIN;            // scalar c_loss
  float* outCB = outL + 1;                              // [K, CIN]
  float* outE  = outCB + (size_t)KCB * CIN;             // [K]

  // workspace layout (total ~3.4 MiB)
  char* w = (char*)d_ws;
  float* wdT  = (float*)(w + 0);          //  65,536 B
  float* wuT  = (float*)(w + 65536);      //  65,536 B
  float* cb2  = (float*)(w + 131072);     //   8,192 B
  int*   dr   = (int*)  (w + 139264);     // 1,310,720 B  draws [10][N]
  int*   cnt  = (int*)  (w + 1449984);    //   8,192 B
  float* clo  = (float*)(w + 1458176);    //     256 B
  float* dwa  = (float*)(w + 1458432);    // 2,097,152 B  dw accum [K][CIN]
  float* emaw = (float*)(w + 3555584);    //   8,192 B

  hipMemsetAsync(cnt, 0, 8192 + 256 + 2097152, stream);

  k_weights<<<128, 256, 0, stream>>>(ad, sd, au, su, wdT, wuT);
  k_cbnorm<<<8, 256, 0, stream>>>(cb, cb2);
  k_pcf<<<NROWS, 256, 0, stream>>>(ge, wdT, bd, wuT, bu, out0);      // pc -> out0 region
  k_sample<<<NROWS / 32, 256, 0, stream>>>(out0, cb, cb2, dr);
  k_dw<<<NROWS, 256, 0, stream>>>(dr, out0, dwa);                    // reads pristine pc
  k_hist<<<64, 256, 0, stream>>>(dr, cnt);
  k_ema<<<1, 256, 0, stream>>>(cnt, ecs, outE, emaw);
  k_out0<<<NROWS, 256, 0, stream>>>(dr, cb, out0, x, pemb, clo);     // in-place transform
  k_final<<<1, 64, 0, stream>>>(clo, outL);
  k_codebook<<<2048, 256, 0, stream>>>(dwa, cb, emaw, outCB);
}

// Round 4
// 1788.421 us; speedup vs baseline: 4.6664x; 1.4086x over previous
//
#include <hip/hip_runtime.h>
#include <cstdint>
#include <cstddef>

// Problem constants
#define NROWS 32768
#define CIN 256
#define CHID 64
#define KCB 2048
#define NSAMP 10

constexpr uint32_t NKu   = 67108864u;   // NROWS*KCB
constexpr uint32_t HALFu = 335544320u;  // 5*NKu (counter offset for second word's draw)

using f32x4 = __attribute__((ext_vector_type(4))) float;
using bf16x8 = __attribute__((ext_vector_type(8))) short;

// ---------------- threefry2x32 (key = jax.random.key(42) -> (0,42)) ----------------
__device__ __forceinline__ void tf2x32(uint32_t x0, uint32_t x1,
                                       uint32_t& o0, uint32_t& o1) {
  constexpr uint32_t K0c = 0u, K1c = 42u;
  constexpr uint32_t K2c = 0x1BD11BDAu ^ K0c ^ K1c;
  const uint32_t ks[3] = {K0c, K1c, K2c};
  x0 += K0c; x1 += K1c;
#pragma unroll
  for (int g = 0; g < 5; ++g) {
    const int R0 = (g & 1) ? 17 : 13;
    const int R1 = (g & 1) ? 29 : 15;
    const int R2 = (g & 1) ? 16 : 26;
    const int R3 = (g & 1) ? 24 : 6;
    x0 += x1; x1 = (x1 << R0) | (x1 >> (32 - R0)); x1 ^= x0;
    x0 += x1; x1 = (x1 << R1) | (x1 >> (32 - R1)); x1 ^= x0;
    x0 += x1; x1 = (x1 << R2) | (x1 >> (32 - R2)); x1 ^= x0;
    x0 += x1; x1 = (x1 << R3) | (x1 >> (32 - R3)); x1 ^= x0;
    x0 += ks[(g + 1) % 3];
    x1 += ks[(g + 2) % 3] + (uint32_t)(g + 1);
  }
  o0 = x0; o1 = x1;
}

__device__ __forceinline__ ushort bf16_rne(float x) {
  uint32_t b = __float_as_uint(x);
  return (ushort)((b + 0x7fffu + ((b >> 16) & 1u)) >> 16);
}
__device__ __forceinline__ float bf16_tof(ushort u) {
  return __uint_as_float(((uint32_t)u) << 16);
}

// ---------------- PHM weights (transposed layouts only) ----------------
__global__ void __launch_bounds__(256) k_weights(
    const float* __restrict__ ad, const float* __restrict__ sd,
    const float* __restrict__ au, const float* __restrict__ su,
    float* __restrict__ wdT, float* __restrict__ wuT) {
  int gid = blockIdx.x * 256 + threadIdx.x;
  if (gid < CHID * CIN) {            // W_down [64][256]
    int r = gid >> 8, c = gid & 255;
    int i = r >> 4, kq = r & 15, j = c >> 6, l = c & 63;
    float acc = 0.f;
#pragma unroll
    for (int n = 0; n < 4; ++n)
      acc = fmaf(ad[n * 16 + i * 4 + j], sd[n * 1024 + kq * 64 + l], acc);
    wdT[c * CHID + r] = acc;
  } else {                           // W_up [256][64]
    int g2 = gid - CHID * CIN;
    int r = g2 >> 6, c = g2 & 63;
    int i = r >> 6, kq = r & 63, j = c >> 4, l = c & 15;
    float acc = 0.f;
#pragma unroll
    for (int n = 0; n < 4; ++n)
      acc = fmaf(au[n * 16 + i * 4 + j], su[n * 1024 + kq * 16 + l], acc);
    wuT[c * CIN + r] = acc;
  }
}

// codebook row norms
__global__ void k_cbnorm(const float* __restrict__ cb, float* __restrict__ cb2) {
  int k = blockIdx.x * blockDim.x + threadIdx.x;
  if (k >= KCB) return;
  const float4* row = (const float4*)(cb + (size_t)k * CIN);
  float acc = 0.f;
  for (int c4 = 0; c4 < CIN / 4; ++c4) {
    float4 v = row[c4];
    acc += v.x * v.x; acc += v.y * v.y; acc += v.z * v.z; acc += v.w * v.w;
  }
  cb2[k] = acc;
}

// Fused PHM: pc[i] = relu(ge[i] @ Wd^T + bd) @ Wu^T + bu   (one block per row)
__global__ void __launch_bounds__(256) k_pcf(
    const float* __restrict__ ge, const float* __restrict__ wdT,
    const float* __restrict__ bd, const float* __restrict__ wuT,
    const float* __restrict__ bu, float* __restrict__ pc) {
  __shared__ float ges[256];
  __shared__ float hp[4][64];
  __shared__ float hs[64];
  int i = blockIdx.x, tid = threadIdx.x;
  ges[tid] = ge[(size_t)i * CIN + tid];
  __syncthreads();
  int r = tid & 63, q = tid >> 6;
  float a = 0.f;
#pragma unroll
  for (int c = 0; c < 64; ++c)
    a = fmaf(ges[q * 64 + c], wdT[(q * 64 + c) * CHID + r], a);
  hp[q][r] = a;
  __syncthreads();
  if (tid < 64) {
    float v = hp[0][tid] + hp[1][tid] + hp[2][tid] + hp[3][tid] + bd[tid];
    hs[tid] = fmaxf(v, 0.f);
  }
  __syncthreads();
  float acc = bu[tid];
#pragma unroll
  for (int kq = 0; kq < CHID; ++kq)
    acc = fmaf(hs[kq], wuT[kq * CIN + tid], acc);
  pc[(size_t)i * CIN + tid] = acc;
}

// ---------------- Two-phase pruned MFMA sampler ----------------
// Phase 1: MFMA scores -> exact per-row smax.  Phase 2: identical MFMA,
// keep only d = score - smax > -18 (P(win|pruned) ~ e^-18), wave-compact
// survivors into LDS queue, drain densely with threefry + exponential race
// val = E * exp(-d) (same winner as gumbel argmax for same uniforms).
__global__ void __launch_bounds__(256) k_sample(
    const float* __restrict__ pc, const float* __restrict__ cb,
    const float* __restrict__ cb2, int* __restrict__ draws) {
  __shared__ __attribute__((aligned(16))) ushort cbs_hi[32][264];
  __shared__ __attribute__((aligned(16))) ushort cbs_lo[32][264];
  __shared__ __attribute__((aligned(16))) ushort pcs_hi[32][264];
  __shared__ __attribute__((aligned(16))) ushort pcs_lo[32][264];
  __shared__ unsigned long long bests[32][NSAMP];
  __shared__ uint32_t q[4][160];
  __shared__ float smax_sh[4][16];
  __shared__ float smax[32];

  int tid = threadIdx.x;
  int w = tid >> 6, lane = tid & 63;
  int ih = w & 1, kh = w >> 1;
  int l15 = lane & 15, lq = lane >> 4;

  // init bests
  for (int e = tid; e < 32 * NSAMP; e += 256)
    ((unsigned long long*)bests)[e] = 0xFFFFFFFFFFFFFFFFull;

  // stage pc tile (32 rows) once: hi + residual-lo bf16
  {
    const float* base = pc + (size_t)blockIdx.x * 32 * CIN;
#pragma unroll
    for (int rep = 0; rep < 8; ++rep) {
      int f = rep * 1024 + tid * 4;
      int row = f >> 8, col = f & 255;
      float4 v = *(const float4*)(base + row * CIN + col);
      ushort4 hh, ll;
      hh.x = bf16_rne(v.x); ll.x = bf16_rne(v.x - bf16_tof(hh.x));
      hh.y = bf16_rne(v.y); ll.y = bf16_rne(v.y - bf16_tof(hh.y));
      hh.z = bf16_rne(v.z); ll.z = bf16_rne(v.z - bf16_tof(hh.z));
      hh.w = bf16_rne(v.w); ll.w = bf16_rne(v.w - bf16_tof(hh.w));
      *(ushort4*)&pcs_hi[row][col] = hh;
      *(ushort4*)&pcs_lo[row][col] = ll;
    }
  }

  int i_loc = l15 + 16 * ih;
  int krow = 16 * kh + l15;       // A-operand row (cb row within tile)

  // ---------------- phase 1: smax ----------------
  float lmax = -3.0e38f;
  for (int t = 0; t < 64; ++t) {
    __syncthreads();
    {
      const float* base = cb + (size_t)t * 32 * CIN;
#pragma unroll
      for (int rep = 0; rep < 8; ++rep) {
        int f = rep * 1024 + tid * 4;
        int row = f >> 8, col = f & 255;
        float4 v = *(const float4*)(base + row * CIN + col);
        ushort4 hh, ll;
        hh.x = bf16_rne(v.x); ll.x = bf16_rne(v.x - bf16_tof(hh.x));
        hh.y = bf16_rne(v.y); ll.y = bf16_rne(v.y - bf16_tof(hh.y));
        hh.z = bf16_rne(v.z); ll.z = bf16_rne(v.z - bf16_tof(hh.z));
        hh.w = bf16_rne(v.w); ll.w = bf16_rne(v.w - bf16_tof(hh.w));
        *(ushort4*)&cbs_hi[row][col] = hh;
        *(ushort4*)&cbs_lo[row][col] = ll;
      }
    }
    __syncthreads();

    f32x4 acc = {0.f, 0.f, 0.f, 0.f};
#pragma unroll
    for (int ks = 0; ks < 8; ++ks) {
      int kk = ks * 32 + 8 * lq;
      bf16x8 ah = *(const bf16x8*)&cbs_hi[krow][kk];
      bf16x8 al = *(const bf16x8*)&cbs_lo[krow][kk];
      bf16x8 bh = *(const bf16x8*)&pcs_hi[i_loc][kk];
      bf16x8 bl = *(const bf16x8*)&pcs_lo[i_loc][kk];
      acc = __builtin_amdgcn_mfma_f32_16x16x32_bf16(ah, bh, acc, 0, 0, 0);
      acc = __builtin_amdgcn_mfma_f32_16x16x32_bf16(al, bh, acc, 0, 0, 0);
      acc = __builtin_amdgcn_mfma_f32_16x16x32_bf16(ah, bl, acc, 0, 0, 0);
    }
    int k0 = t * 32 + 16 * kh + 4 * lq;
#pragma unroll
    for (int r = 0; r < 4; ++r) {
      float score = 2.0f * acc[r] - cb2[k0 + r];
      lmax = fmaxf(lmax, score);
    }
  }
  // reduce lmax over the 4 lq groups (same i)
  lmax = fmaxf(lmax, __shfl_xor(lmax, 16, 64));
  lmax = fmaxf(lmax, __shfl_xor(lmax, 32, 64));
  if (lane < 16) smax_sh[w][lane] = lmax;
  __syncthreads();
  if (tid < 32) smax[tid] = fmaxf(smax_sh[tid >> 4][tid & 15],
                                  smax_sh[(tid >> 4) + 2][tid & 15]);
  __syncthreads();
  float mysmax = smax[i_loc];
  uint32_t i0k = (uint32_t)(blockIdx.x * 32) * (uint32_t)KCB;

  // ---------------- phase 2: prune + race ----------------
  int qtail = 0;
  unsigned long long lmask = (lane == 63) ? 0x7FFFFFFFFFFFFFFFull
                                          : ((1ull << lane) - 1ull);
  for (int t = 0; t < 64; ++t) {
    __syncthreads();
    {
      const float* base = cb + (size_t)t * 32 * CIN;
#pragma unroll
      for (int rep = 0; rep < 8; ++rep) {
        int f = rep * 1024 + tid * 4;
        int row = f >> 8, col = f & 255;
        float4 v = *(const float4*)(base + row * CIN + col);
        ushort4 hh, ll;
        hh.x = bf16_rne(v.x); ll.x = bf16_rne(v.x - bf16_tof(hh.x));
        hh.y = bf16_rne(v.y); ll.y = bf16_rne(v.y - bf16_tof(hh.y));
        hh.z = bf16_rne(v.z); ll.z = bf16_rne(v.z - bf16_tof(hh.z));
        hh.w = bf16_rne(v.w); ll.w = bf16_rne(v.w - bf16_tof(hh.w));
        *(ushort4*)&cbs_hi[row][col] = hh;
        *(ushort4*)&cbs_lo[row][col] = ll;
      }
    }
    __syncthreads();

    f32x4 acc = {0.f, 0.f, 0.f, 0.f};
#pragma unroll
    for (int ks = 0; ks < 8; ++ks) {
      int kk = ks * 32 + 8 * lq;
      bf16x8 ah = *(const bf16x8*)&cbs_hi[krow][kk];
      bf16x8 al = *(const bf16x8*)&cbs_lo[krow][kk];
      bf16x8 bh = *(const bf16x8*)&pcs_hi[i_loc][kk];
      bf16x8 bl = *(const bf16x8*)&pcs_lo[i_loc][kk];
      acc = __builtin_amdgcn_mfma_f32_16x16x32_bf16(ah, bh, acc, 0, 0, 0);
      acc = __builtin_amdgcn_mfma_f32_16x16x32_bf16(al, bh, acc, 0, 0, 0);
      acc = __builtin_amdgcn_mfma_f32_16x16x32_bf16(ah, bl, acc, 0, 0, 0);
    }
    int k0 = t * 32 + 16 * kh + 4 * lq;
#pragma unroll
    for (int r = 0; r < 4; ++r) {
      int k = k0 + r;
      float d = 2.0f * acc[r] - cb2[k] - mysmax;   // <= 0; 0 at the row max
      bool pass = d > -18.0f;
      unsigned long long mask = __ballot(pass);
      if (pass) {
        int off = __popcll(mask & lmask);
        uint32_t dq = (uint32_t)(fmaf(d, -3600.0f, 0.5f));   // fixed-point, 1/3600
        q[w][qtail + off] = (dq << 16) | ((uint32_t)i_loc << 11) | (uint32_t)k;
      }
      qtail += (int)__popcll(mask);
      if (qtail >= 64) {
        for (int j = lane; j < qtail; j += 64) {
          uint32_t it = q[w][j];
          int kk2 = it & 2047;
          int il = (it >> 11) & 31;
          float d2 = (float)(it >> 16) * (-1.0f / 3600.0f);
          float sc = __expf(-d2);
          uint32_t kb = i0k + (uint32_t)il * KCB + (uint32_t)kk2;
#pragma unroll
          for (int s5 = 0; s5 < 5; ++s5) {
            uint32_t blk = (uint32_t)s5 * NKu + kb;
            uint32_t o0, o1;
            tf2x32(blk, blk + HALFu, o0, o1);
            float u0 = __uint_as_float((o0 >> 9) | 0x3f800000u) - 1.0f;
            float u1 = __uint_as_float((o1 >> 9) | 0x3f800000u) - 1.0f;
            float E0 = -__logf(fmaxf(u0, 1.17549435e-38f));
            float E1 = -__logf(fmaxf(u1, 1.17549435e-38f));
            unsigned long long p0 =
                (((unsigned long long)__float_as_uint(E0 * sc)) << 32) | (uint32_t)kk2;
            unsigned long long p1 =
                (((unsigned long long)__float_as_uint(E1 * sc)) << 32) | (uint32_t)kk2;
            atomicMin(&bests[il][s5], p0);
            atomicMin(&bests[il][s5 + 5], p1);
          }
        }
        qtail = 0;
      }
    }
  }
  // final drain
  for (int j = lane; j < qtail; j += 64) {
    uint32_t it = q[w][j];
    int kk2 = it & 2047;
    int il = (it >> 11) & 31;
    float d2 = (float)(it >> 16) * (-1.0f / 3600.0f);
    float sc = __expf(-d2);
    uint32_t kb = i0k + (uint32_t)il * KCB + (uint32_t)kk2;
#pragma unroll
    for (int s5 = 0; s5 < 5; ++s5) {
      uint32_t blk = (uint32_t)s5 * NKu + kb;
      uint32_t o0, o1;
      tf2x32(blk, blk + HALFu, o0, o1);
      float u0 = __uint_as_float((o0 >> 9) | 0x3f800000u) - 1.0f;
      float u1 = __uint_as_float((o1 >> 9) | 0x3f800000u) - 1.0f;
      float E0 = -__logf(fmaxf(u0, 1.17549435e-38f));
      float E1 = -__logf(fmaxf(u1, 1.17549435e-38f));
      unsigned long long p0 =
          (((unsigned long long)__float_as_uint(E0 * sc)) << 32) | (uint32_t)kk2;
      unsigned long long p1 =
          (((unsigned long long)__float_as_uint(E1 * sc)) << 32) | (uint32_t)kk2;
      atomicMin(&bests[il][s5], p0);
      atomicMin(&bests[il][s5 + 5], p1);
    }
  }
  __syncthreads();
  for (int item = tid; item < 32 * NSAMP; item += 256) {
    int il = item / NSAMP, s = item % NSAMP;
    draws[s * NROWS + blockIdx.x * 32 + il] =
        (int)((uint32_t)(bests[il][s] & 0xFFFFFFFFull) & 2047u);
  }
}

// static sorting network (compile-time indices -> registers)
__device__ __forceinline__ void load_sorted_draws(const int* dl, int* d) {
#pragma unroll
  for (int s = 0; s < NSAMP; ++s) d[s] = dl[s];
#pragma unroll
  for (int p = 0; p < NSAMP - 1; ++p)
#pragma unroll
    for (int a = 0; a < NSAMP - 1 - p; ++a) {
      int lo = min(d[a], d[a + 1]);
      int hi = max(d[a], d[a + 1]);
      d[a] = lo; d[a + 1] = hi;
    }
}

// dw[k][c] += count * pc[i][c]  (atomic fp32)
__global__ void __launch_bounds__(256) k_dw(const int* __restrict__ draws,
                                            const float* __restrict__ pc,
                                            float* __restrict__ dw) {
  __shared__ int dl[NSAMP];
  int i = blockIdx.x, tid = threadIdx.x;
  if (tid < NSAMP) dl[tid] = draws[tid * NROWS + i];
  __syncthreads();
  int d[NSAMP];
  load_sorted_draws(dl, d);
  float pcv = pc[(size_t)i * CIN + tid];
#pragma unroll
  for (int a = 0; a < NSAMP; ++a) {
    bool first = (a == 0) || (d[a] != d[a - 1]);
    if (first) {
      int c = 1;
#pragma unroll
      for (int b2 = a + 1; b2 < NSAMP; ++b2) c += (d[b2] == d[a]) ? 1 : 0;
      atomicAdd(&dw[(size_t)d[a] * CIN + tid], (float)c * pcv);
    }
  }
}

// out0 = x + (p_c + (p_q - p_c)) + p_emb, in place over pc buffer; c_loss partials
__global__ void __launch_bounds__(256) k_out0(
    const int* __restrict__ draws, const float* __restrict__ cb,
    float* __restrict__ pc_out0, const float* __restrict__ x,
    const float* __restrict__ pemb, float* __restrict__ closs) {
  __shared__ int dl[NSAMP];
  __shared__ float red[256];
  int i = blockIdx.x, tid = threadIdx.x;
  if (tid < NSAMP) dl[tid] = draws[tid * NROWS + i];
  __syncthreads();
  int d[NSAMP];
  load_sorted_draws(dl, d);
  float acc = 0.f;
#pragma unroll
  for (int a = 0; a < NSAMP; ++a) {
    bool first = (a == 0) || (d[a] != d[a - 1]);
    if (first) {
      int c = 1;
#pragma unroll
      for (int b2 = a + 1; b2 < NSAMP; ++b2) c += (d[b2] == d[a]) ? 1 : 0;
      acc = fmaf((float)c, cb[(size_t)d[a] * CIN + tid], acc);
    }
  }
  float pq  = acc / 10.0f;
  float pcv = pc_out0[(size_t)i * CIN + tid];
  float t   = pq - pcv;
  float pr  = (pcv + t) + pemb[tid];
  pc_out0[(size_t)i * CIN + tid] = x[(size_t)i * CIN + tid] + pr;
  red[tid] = t * t;
  __syncthreads();
  for (int off = 128; off > 0; off >>= 1) {
    if (tid < off) red[tid] += red[tid + off];
    __syncthreads();
  }
  if (tid == 0) atomicAdd(closs, red[0]);
}

__global__ void k_final(const float* __restrict__ closs, float* __restrict__ dst) {
  if (blockIdx.x == 0 && threadIdx.x == 0) dst[0] = closs[0] / 8388608.0f;
}

// per-k draw counts via LDS histogram
__global__ void __launch_bounds__(256) k_hist(const int* __restrict__ draws,
                                              int* __restrict__ counts) {
  __shared__ int hist[KCB];
  for (int b = threadIdx.x; b < KCB; b += 256) hist[b] = 0;
  __syncthreads();
  const int total = NSAMP * NROWS;
  for (int idx = blockIdx.x * 256 + threadIdx.x; idx < total; idx += gridDim.x * 256)
    atomicAdd(&hist[draws[idx]], 1);
  __syncthreads();
  for (int b = threadIdx.x; b < KCB; b += 256)
    if (hist[b]) atomicAdd(&counts[b], hist[b]);
}

// EMA cluster-size update (single block for deterministic n_tot)
__global__ void __launch_bounds__(256) k_ema(
    const int* __restrict__ counts, const float* __restrict__ ecs,
    float* __restrict__ ema_dst, float* __restrict__ ema_ws) {
  __shared__ float e_sh[KCB];
  __shared__ float red[256];
  int tid = threadIdx.x;
  float psum = 0.f;
  for (int k = tid; k < KCB; k += 256) {
    float s10 = (float)counts[k] / 10.0f;
    float e = ecs[k] * 0.9f + 0.1f * s10;
    e_sh[k] = e;
    psum += e;
  }
  red[tid] = psum;
  __syncthreads();
  for (int off = 128; off > 0; off >>= 1) {
    if (tid < off) red[tid] += red[tid + off];
    __syncthreads();
  }
  float ntot = red[0];
  float denom = ntot + 20.48f;   // K * EPS
  for (int k = tid; k < KCB; k += 256) {
    float v = (e_sh[k] + 0.01f) / denom * ntot;
    ema_dst[k] = v;
    ema_ws[k]  = v;
  }
}

// new_codebook = cb*0.9 + 0.1*((dw/10) / ema)
__global__ void k_codebook(const float* __restrict__ dw,
                           const float* __restrict__ cb,
                           const float* __restrict__ ema_ws,
                           float* __restrict__ out_cb) {
  int gid = blockIdx.x * blockDim.x + threadIdx.x;
  if (gid >= KCB * CIN) return;
  int k = gid >> 8;
  float dw10 = dw[gid] / 10.0f;
  float ratio = dw10 / ema_ws[k];
  out_cb[gid] = cb[gid] * 0.9f + 0.1f * ratio;
}

extern "C" void kernel_launch(void* const* d_in, const int* in_sizes, int n_in,
                              void* d_out, int out_size, void* d_ws, size_t ws_size,
                              hipStream_t stream) {
  (void)in_sizes; (void)n_in; (void)out_size; (void)ws_size;
  const float* x    = (const float*)d_in[0];
  const float* ge   = (const float*)d_in[1];
  const float* pemb = (const float*)d_in[2];
  const float* cb   = (const float*)d_in[3];
  const float* ecs  = (const float*)d_in[4];
  const float* ad   = (const float*)d_in[5];
  const float* sd   = (const float*)d_in[6];
  const float* bd   = (const float*)d_in[7];
  const float* au   = (const float*)d_in[8];
  const float* su   = (const float*)d_in[9];
  const float* bu   = (const float*)d_in[10];

  float* out0  = (float*)d_out;                         // [N, CIN]; doubles as pc scratch
  float* outL  = out0 + (size_t)NROWS * CIN;            // scalar c_loss
  float* outCB = outL + 1;                              // [K, CIN]
  float* outE  = outCB + (size_t)KCB * CIN;             // [K]

  // workspace layout (total ~3.4 MiB)
  char* w = (char*)d_ws;
  float* wdT  = (float*)(w + 0);          //  65,536 B
  float* wuT  = (float*)(w + 65536);      //  65,536 B
  float* cb2  = (float*)(w + 131072);     //   8,192 B
  int*   dr   = (int*)  (w + 139264);     // 1,310,720 B  draws [10][N]
  int*   cnt  = (int*)  (w + 1449984);    //   8,192 B
  float* clo  = (float*)(w + 1458176);    //     256 B
  float* dwa  = (float*)(w + 1458432);    // 2,097,152 B  dw accum [K][CIN]
  float* emaw = (float*)(w + 3555584);    //   8,192 B

  hipMemsetAsync(cnt, 0, 8192 + 256 + 2097152, stream);

  k_weights<<<128, 256, 0, stream>>>(ad, sd, au, su, wdT, wuT);
  k_cbnorm<<<8, 256, 0, stream>>>(cb, cb2);
  k_pcf<<<NROWS, 256, 0, stream>>>(ge, wdT, bd, wuT, bu, out0);      // pc -> out0 region
  k_sample<<<NROWS / 32, 256, 0, stream>>>(out0, cb, cb2, dr);
  k_dw<<<NROWS, 256, 0, stream>>>(dr, out0, dwa);                    // reads pristine pc
  k_hist<<<64, 256, 0, stream>>>(dr, cnt);
  k_ema<<<1, 256, 0, stream>>>(cnt, ecs, outE, emaw);
  k_out0<<<NROWS, 256, 0, stream>>>(dr, cb, out0, x, pemb, clo);     // in-place transform
  k_final<<<1, 64, 0, stream>>>(clo, outL);
  k_codebook<<<2048, 256, 0, stream>>>(dwa, cb, emaw, outCB);
}

// Round 5
// 1017.319 us; speedup vs baseline: 8.2035x; 1.7580x over previous
//
#include <hip/hip_runtime.h>
#include <cstdint>
#include <cstddef>

// Problem constants
#define NROWS 32768
#define CIN 256
#define CHID 64
#define KCB 2048
#define NSAMP 10

constexpr uint32_t NKu   = 67108864u;   // NROWS*KCB
constexpr uint32_t HALFu = 335544320u;  // 5*NKu (counter offset for second word's draw)

using f32x4 = __attribute__((ext_vector_type(4))) float;
using bf16x8 = __attribute__((ext_vector_type(8))) short;

// ---------------- threefry2x32 (key = jax.random.key(42) -> (0,42)) ----------------
__device__ __forceinline__ void tf2x32(uint32_t x0, uint32_t x1,
                                       uint32_t& o0, uint32_t& o1) {
  constexpr uint32_t K0c = 0u, K1c = 42u;
  constexpr uint32_t K2c = 0x1BD11BDAu ^ K0c ^ K1c;
  const uint32_t ks[3] = {K0c, K1c, K2c};
  x0 += K0c; x1 += K1c;
#pragma unroll
  for (int g = 0; g < 5; ++g) {
    const int R0 = (g & 1) ? 17 : 13;
    const int R1 = (g & 1) ? 29 : 15;
    const int R2 = (g & 1) ? 16 : 26;
    const int R3 = (g & 1) ? 24 : 6;
    x0 += x1; x1 = (x1 << R0) | (x1 >> (32 - R0)); x1 ^= x0;
    x0 += x1; x1 = (x1 << R1) | (x1 >> (32 - R1)); x1 ^= x0;
    x0 += x1; x1 = (x1 << R2) | (x1 >> (32 - R2)); x1 ^= x0;
    x0 += x1; x1 = (x1 << R3) | (x1 >> (32 - R3)); x1 ^= x0;
    x0 += ks[(g + 1) % 3];
    x1 += ks[(g + 2) % 3] + (uint32_t)(g + 1);
  }
  o0 = x0; o1 = x1;
}

__device__ __forceinline__ ushort bf16_rne(float x) {
  uint32_t b = __float_as_uint(x);
  return (ushort)((b + 0x7fffu + ((b >> 16) & 1u)) >> 16);
}
__device__ __forceinline__ float bf16_tof(ushort u) {
  return __uint_as_float(((uint32_t)u) << 16);
}

// float <-> order-preserving uint (for atomicMin/Max races on signed floats)
__device__ __forceinline__ uint32_t fenc(float f) {
  uint32_t u = __float_as_uint(f);
  return (u & 0x80000000u) ? ~u : (u | 0x80000000u);
}
__device__ __forceinline__ float fdec(uint32_t e) {
  uint32_t u = (e & 0x80000000u) ? (e ^ 0x80000000u) : ~e;
  return __uint_as_float(u);
}

// ---------------- PHM weights (transposed layouts only) ----------------
__global__ void __launch_bounds__(256) k_weights(
    const float* __restrict__ ad, const float* __restrict__ sd,
    const float* __restrict__ au, const float* __restrict__ su,
    float* __restrict__ wdT, float* __restrict__ wuT) {
  int gid = blockIdx.x * 256 + threadIdx.x;
  if (gid < CHID * CIN) {            // W_down [64][256]
    int r = gid >> 8, c = gid & 255;
    int i = r >> 4, kq = r & 15, j = c >> 6, l = c & 63;
    float acc = 0.f;
#pragma unroll
    for (int n = 0; n < 4; ++n)
      acc = fmaf(ad[n * 16 + i * 4 + j], sd[n * 1024 + kq * 64 + l], acc);
    wdT[c * CHID + r] = acc;
  } else {                           // W_up [256][64]
    int g2 = gid - CHID * CIN;
    int r = g2 >> 6, c = g2 & 63;
    int i = r >> 6, kq = r & 63, j = c >> 4, l = c & 15;
    float acc = 0.f;
#pragma unroll
    for (int n = 0; n < 4; ++n)
      acc = fmaf(au[n * 16 + i * 4 + j], su[n * 1024 + kq * 16 + l], acc);
    wuT[c * CIN + r] = acc;
  }
}

// cb prep: row norms + lane-tiled bf16 hi/lo layout for coalesced MFMA A-frags.
// dest idx = (((t*2+kh)*8 + ks)*64 + lq*16 + l15)*8 + e
//   <-> cb[t*32 + 16*kh + l15][ks*32 + 8*lq + e]
__global__ void __launch_bounds__(256) k_cbprep(
    const float* __restrict__ cb, float* __restrict__ cb2,
    ushort* __restrict__ th, ushort* __restrict__ tl) {
  __shared__ float wsum[4];
  int k = blockIdx.x, c = threadIdx.x;
  float v = cb[(size_t)k * CIN + c];
  float sq = v * v;
#pragma unroll
  for (int m = 1; m < 64; m <<= 1) sq += __shfl_xor(sq, m, 64);
  if ((c & 63) == 0) wsum[c >> 6] = sq;
  __syncthreads();
  if (c == 0) cb2[k] = wsum[0] + wsum[1] + wsum[2] + wsum[3];
  ushort hi = bf16_rne(v);
  ushort lo = bf16_rne(v - bf16_tof(hi));
  int t = k >> 5, r5 = k & 31, kh = r5 >> 4, l15 = r5 & 15;
  int ks = c >> 5, c5 = c & 31, lq = c5 >> 3, e = c5 & 7;
  size_t di = (size_t)((((t * 2 + kh) * 8 + ks) * 64) + lq * 16 + l15) * 8 + e;
  th[di] = hi; tl[di] = lo;
}

// Fused PHM: pc[i] = relu(ge[i] @ Wd^T + bd) @ Wu^T + bu   (one block per row)
__global__ void __launch_bounds__(256) k_pcf(
    const float* __restrict__ ge, const float* __restrict__ wdT,
    const float* __restrict__ bd, const float* __restrict__ wuT,
    const float* __restrict__ bu, float* __restrict__ pc) {
  __shared__ float ges[256];
  __shared__ float hp[4][64];
  __shared__ float hs[64];
  int i = blockIdx.x, tid = threadIdx.x;
  ges[tid] = ge[(size_t)i * CIN + tid];
  __syncthreads();
  int r = tid & 63, q = tid >> 6;
  float a = 0.f;
#pragma unroll
  for (int c = 0; c < 64; ++c)
    a = fmaf(ges[q * 64 + c], wdT[(q * 64 + c) * CHID + r], a);
  hp[q][r] = a;
  __syncthreads();
  if (tid < 64) {
    float v = hp[0][tid] + hp[1][tid] + hp[2][tid] + hp[3][tid] + bd[tid];
    hs[tid] = fmaxf(v, 0.f);
  }
  __syncthreads();
  float acc = bu[tid];
#pragma unroll
  for (int kq = 0; kq < CHID; ++kq)
    acc = fmaf(hs[kq], wuT[kq * CIN + tid], acc);
  pc[(size_t)i * CIN + tid] = acc;
}

// ---------------- drain helper: exact threefry + log-race ----------------
// winner of draw s = argmax(score + Gumbel) = argmin(log E - score), E=-log U
__device__ __forceinline__ void drain_q(
    const unsigned long long* qw, int n, int lane, uint32_t i0k,
    unsigned long long (*bests)[NSAMP]) {
  for (int j = lane; j < n; j += 64) {
    unsigned long long e = qw[j];
    float score = __uint_as_float((uint32_t)(e >> 32));
    int il = (int)((e >> 11) & 31u);
    int k  = (int)(e & 2047u);
    uint32_t kb = i0k + (uint32_t)il * KCB + (uint32_t)k;
#pragma unroll
    for (int s5 = 0; s5 < 5; ++s5) {
      uint32_t blk = (uint32_t)s5 * NKu + kb;
      uint32_t o0, o1;
      tf2x32(blk, blk + HALFu, o0, o1);
      float u0 = __uint_as_float((o0 >> 9) | 0x3f800000u) - 1.0f;
      float u1 = __uint_as_float((o1 >> 9) | 0x3f800000u) - 1.0f;
      float E0 = -__logf(fmaxf(u0, 1.17549435e-38f));
      float E1 = -__logf(fmaxf(u1, 1.17549435e-38f));
      float v0 = __logf(E0) - score;
      float v1 = __logf(E1) - score;
      unsigned long long p0 = (((unsigned long long)fenc(v0)) << 32) | (uint32_t)k;
      unsigned long long p1 = (((unsigned long long)fenc(v1)) << 32) | (uint32_t)k;
      atomicMin(&bests[il][s5], p0);
      atomicMin(&bests[il][s5 + 5], p1);
    }
  }
}

// ---------------- Single-pass pruned MFMA sampler ----------------
// 32 rows/block. pc frags in registers; cb frags direct from lane-tiled global
// (coalesced 16B/lane); online row-max prune (conservative); log-race drain.
__global__ void __launch_bounds__(256, 3) k_sample(
    const float* __restrict__ pc, const ushort* __restrict__ th,
    const ushort* __restrict__ tl, const float* __restrict__ cb2,
    int* __restrict__ draws) {
  __shared__ unsigned long long bests[32][NSAMP];
  __shared__ unsigned long long q[4][128];
  __shared__ uint32_t menc[32];
  __shared__ float bias2[KCB];

  int tid = threadIdx.x;
  int w = tid >> 6, lane = tid & 63;
  int ih = w & 1, kh = w >> 1;
  int l15 = lane & 15, lq = lane >> 4;

  for (int e = tid; e < 32 * NSAMP; e += 256)
    ((unsigned long long*)bests)[e] = ~0ull;
  if (tid < 32) menc[tid] = 0u;
  for (int kk = tid; kk < KCB; kk += 256) bias2[kk] = -0.5f * cb2[kk];

  int i_loc = l15 + 16 * ih;
  int i_abs = blockIdx.x * 32 + i_loc;

  // pc fragments (hi + residual lo), registers: 16 x bf16x8
  bf16x8 pch[8], pcl[8];
  {
    const float* prow = pc + (size_t)i_abs * CIN;
#pragma unroll
    for (int ks = 0; ks < 8; ++ks) {
      float4 a = *(const float4*)(prow + ks * 32 + 8 * lq);
      float4 b = *(const float4*)(prow + ks * 32 + 8 * lq + 4);
      float vv[8] = {a.x, a.y, a.z, a.w, b.x, b.y, b.z, b.w};
#pragma unroll
      for (int e = 0; e < 8; ++e) {
        ushort hi = bf16_rne(vv[e]);
        pch[ks][e] = (short)hi;
        pcl[ks][e] = (short)bf16_rne(vv[e] - bf16_tof(hi));
      }
    }
  }
  __syncthreads();

  uint32_t i0k = (uint32_t)(blockIdx.x * 32) * (uint32_t)KCB;
  int qtail = 0;
  unsigned long long lmask = (1ull << lane) - 1ull;

  for (int t = 0; t < 64; ++t) {
    const ushort* ph = th + (size_t)((t * 2 + kh) * 8) * 512 + lane * 8;
    const ushort* pl = tl + (size_t)((t * 2 + kh) * 8) * 512 + lane * 8;
    int k0 = t * 32 + 16 * kh + 4 * lq;
    f32x4 acc = *(const f32x4*)&bias2[k0];   // init with -0.5*||cb_k||^2
#pragma unroll
    for (int ks = 0; ks < 8; ++ks) {
      bf16x8 ah = *(const bf16x8*)(ph + ks * 512);
      bf16x8 al = *(const bf16x8*)(pl + ks * 512);
      acc = __builtin_amdgcn_mfma_f32_16x16x32_bf16(ah, pch[ks], acc, 0, 0, 0);
      acc = __builtin_amdgcn_mfma_f32_16x16x32_bf16(al, pch[ks], acc, 0, 0, 0);
      acc = __builtin_amdgcn_mfma_f32_16x16x32_bf16(ah, pcl[ks], acc, 0, 0, 0);
    }
    float sc[4];
#pragma unroll
    for (int r = 0; r < 4; ++r) sc[r] = 2.0f * acc[r];   // = 2*dot - cb2

    // online row max (conservative prune threshold)
    float mx = fmaxf(fmaxf(sc[0], sc[1]), fmaxf(sc[2], sc[3]));
    mx = fmaxf(mx, __shfl_xor(mx, 16, 64));
    mx = fmaxf(mx, __shfl_xor(mx, 32, 64));
    if (lane < 16) atomicMax(&menc[i_loc], fenc(mx));
    float thr = fdec(menc[i_loc]) - 18.0f;

#pragma unroll
    for (int r = 0; r < 4; ++r) {
      bool pass = sc[r] > thr;
      unsigned long long mask = __ballot(pass);
      if (pass) {
        int off = __popcll(mask & lmask);
        q[w][qtail + off] =
            (((unsigned long long)__float_as_uint(sc[r])) << 32) |
            ((unsigned long long)(uint32_t)i_loc << 11) |
            (unsigned long long)(uint32_t)(k0 + r);
      }
      qtail += (int)__popcll(mask);
      if (qtail >= 64) { drain_q(q[w], qtail, lane, i0k, bests); qtail = 0; }
    }
  }
  drain_q(q[w], qtail, lane, i0k, bests);
  __syncthreads();
  for (int item = tid; item < 32 * NSAMP; item += 256) {
    int il = item / NSAMP, s = item % NSAMP;
    draws[s * NROWS + blockIdx.x * 32 + il] =
        (int)((uint32_t)(bests[il][s] & 0xFFFFFFFFull) & 2047u);
  }
}

// static sorting network (compile-time indices -> registers)
__device__ __forceinline__ void load_sorted_draws(const int* dl, int* d) {
#pragma unroll
  for (int s = 0; s < NSAMP; ++s) d[s] = dl[s];
#pragma unroll
  for (int p = 0; p < NSAMP - 1; ++p)
#pragma unroll
    for (int a = 0; a < NSAMP - 1 - p; ++a) {
      int lo = min(d[a], d[a + 1]);
      int hi = max(d[a], d[a + 1]);
      d[a] = lo; d[a + 1] = hi;
    }
}

// fallback dw (atomic-per-row) if workspace is too small for sort path
__global__ void __launch_bounds__(256) k_dw(const int* __restrict__ draws,
                                            const float* __restrict__ pc,
                                            float* __restrict__ dw) {
  __shared__ int dl[NSAMP];
  int i = blockIdx.x, tid = threadIdx.x;
  if (tid < NSAMP) dl[tid] = draws[tid * NROWS + i];
  __syncthreads();
  int d[NSAMP];
  load_sorted_draws(dl, d);
  float pcv = pc[(size_t)i * CIN + tid];
#pragma unroll
  for (int a = 0; a < NSAMP; ++a) {
    bool first = (a == 0) || (d[a] != d[a - 1]);
    if (first) {
      int c = 1;
#pragma unroll
      for (int b2 = a + 1; b2 < NSAMP; ++b2) c += (d[b2] == d[a]) ? 1 : 0;
      atomicAdd(&dw[(size_t)d[a] * CIN + tid], (float)c * pcv);
    }
  }
}

// per-k draw counts via LDS histogram
__global__ void __launch_bounds__(256) k_hist(const int* __restrict__ draws,
                                              int* __restrict__ counts) {
  __shared__ int hist[KCB];
  for (int b = threadIdx.x; b < KCB; b += 256) hist[b] = 0;
  __syncthreads();
  const int total = NSAMP * NROWS;
  for (int idx = blockIdx.x * 256 + threadIdx.x; idx < total; idx += gridDim.x * 256)
    atomicAdd(&hist[draws[idx]], 1);
  __syncthreads();
  for (int b = threadIdx.x; b < KCB; b += 256)
    if (hist[b]) atomicAdd(&counts[b], hist[b]);
}

// exclusive scan of counts -> off, cur
__global__ void k_scan(const int* __restrict__ cnt, int* __restrict__ off,
                       int* __restrict__ cur) {
  __shared__ int part[256];
  __shared__ int pref[256];
  int tid = threadIdx.x;
  int loc[8];
  int s = 0;
  int base = tid * 8;
#pragma unroll
  for (int j = 0; j < 8; ++j) { loc[j] = cnt[base + j]; s += loc[j]; }
  part[tid] = s;
  __syncthreads();
  if (tid == 0) {
    int a = 0;
    for (int i2 = 0; i2 < 256; ++i2) { pref[i2] = a; a += part[i2]; }
  }
  __syncthreads();
  int a = pref[tid];
#pragma unroll
  for (int j = 0; j < 8; ++j) { off[base + j] = a; cur[base + j] = a; a += loc[j]; }
}

// counting-sort scatter: draws -> (rows_sorted, keys_sorted) grouped by k
__global__ void __launch_bounds__(256) k_scatter(const int* __restrict__ dr,
                                                 int* __restrict__ cur,
                                                 int* __restrict__ rows,
                                                 int* __restrict__ keys) {
  __shared__ int h[KCB];
  __shared__ int basek[KCB];
  int tid = threadIdx.x;
  for (int k = tid; k < KCB; k += 256) h[k] = 0;
  __syncthreads();
  int f0 = blockIdx.x * 5120;
  for (int j = tid; j < 5120; j += 256) atomicAdd(&h[dr[f0 + j]], 1);
  __syncthreads();
  for (int k = tid; k < KCB; k += 256) {
    int hv = h[k];
    basek[k] = hv ? atomicAdd(&cur[k], hv) : 0;
    h[k] = 0;
  }
  __syncthreads();
  for (int j = tid; j < 5120; j += 256) {
    int k = dr[f0 + j];
    int li = atomicAdd(&h[k], 1);
    int pos = basek[k] + li;
    rows[pos] = (f0 + j) & (NROWS - 1);
    keys[pos] = k;
  }
}

// segment gather: dw[k] += sum of pc rows (128 entries/block, 1 flush per k-run)
__global__ void __launch_bounds__(256) k_dwgather(const int* __restrict__ rows,
                                                  const int* __restrict__ keys,
                                                  const float* __restrict__ pc,
                                                  float* __restrict__ dw) {
  __shared__ int kk[128];
  __shared__ int rr[128];
  int tid = threadIdx.x;
  int j0 = blockIdx.x * 128;
  if (tid < 128) { kk[tid] = keys[j0 + tid]; rr[tid] = rows[j0 + tid]; }
  __syncthreads();
  int c = tid;
  float acc = 0.f;
  int kprev = kk[0];
  for (int j = 0; j < 128; ++j) {
    int k = kk[j];
    if (k != kprev) {
      atomicAdd(&dw[(size_t)kprev * CIN + c], acc);
      acc = 0.f; kprev = k;
    }
    acc += pc[(size_t)rr[j] * CIN + c];
  }
  atomicAdd(&dw[(size_t)kprev * CIN + c], acc);
}

// out0 = x + (p_c + (p_q - p_c)) + p_emb, in place over pc buffer; c_loss partials
__global__ void __launch_bounds__(256) k_out0(
    const int* __restrict__ draws, const float* __restrict__ cb,
    float* __restrict__ pc_out0, const float* __restrict__ x,
    const float* __restrict__ pemb, float* __restrict__ closs) {
  __shared__ int dl[NSAMP];
  __shared__ float red[256];
  int i = blockIdx.x, tid = threadIdx.x;
  if (tid < NSAMP) dl[tid] = draws[tid * NROWS + i];
  __syncthreads();
  int d[NSAMP];
  load_sorted_draws(dl, d);
  float acc = 0.f;
#pragma unroll
  for (int a = 0; a < NSAMP; ++a) {
    bool first = (a == 0) || (d[a] != d[a - 1]);
    if (first) {
      int c = 1;
#pragma unroll
      for (int b2 = a + 1; b2 < NSAMP; ++b2) c += (d[b2] == d[a]) ? 1 : 0;
      acc = fmaf((float)c, cb[(size_t)d[a] * CIN + tid], acc);
    }
  }
  float pq  = acc / 10.0f;
  float pcv = pc_out0[(size_t)i * CIN + tid];
  float t   = pq - pcv;
  float pr  = (pcv + t) + pemb[tid];
  pc_out0[(size_t)i * CIN + tid] = x[(size_t)i * CIN + tid] + pr;
  red[tid] = t * t;
  __syncthreads();
  for (int off = 128; off > 0; off >>= 1) {
    if (tid < off) red[tid] += red[tid + off];
    __syncthreads();
  }
  if (tid == 0) atomicAdd(closs, red[0]);
}

__global__ void k_final(const float* __restrict__ closs, float* __restrict__ dst) {
  if (blockIdx.x == 0 && threadIdx.x == 0) dst[0] = closs[0] / 8388608.0f;
}

// EMA cluster-size update (single block for deterministic n_tot)
__global__ void __launch_bounds__(256) k_ema(
    const int* __restrict__ counts, const float* __restrict__ ecs,
    float* __restrict__ ema_dst, float* __restrict__ ema_ws) {
  __shared__ float e_sh[KCB];
  __shared__ float red[256];
  int tid = threadIdx.x;
  float psum = 0.f;
  for (int k = tid; k < KCB; k += 256) {
    float s10 = (float)counts[k] / 10.0f;
    float e = ecs[k] * 0.9f + 0.1f * s10;
    e_sh[k] = e;
    psum += e;
  }
  red[tid] = psum;
  __syncthreads();
  for (int off = 128; off > 0; off >>= 1) {
    if (tid < off) red[tid] += red[tid + off];
    __syncthreads();
  }
  float ntot = red[0];
  float denom = ntot + 20.48f;   // K * EPS
  for (int k = tid; k < KCB; k += 256) {
    float v = (e_sh[k] + 0.01f) / denom * ntot;
    ema_dst[k] = v;
    ema_ws[k]  = v;
  }
}

// new_codebook = cb*0.9 + 0.1*((dw/10) / ema)
__global__ void k_codebook(const float* __restrict__ dw,
                           const float* __restrict__ cb,
                           const float* __restrict__ ema_ws,
                           float* __restrict__ out_cb) {
  int gid = blockIdx.x * blockDim.x + threadIdx.x;
  if (gid >= KCB * CIN) return;
  int k = gid >> 8;
  float dw10 = dw[gid] / 10.0f;
  float ratio = dw10 / ema_ws[k];
  out_cb[gid] = cb[gid] * 0.9f + 0.1f * ratio;
}

extern "C" void kernel_launch(void* const* d_in, const int* in_sizes, int n_in,
                              void* d_out, int out_size, void* d_ws, size_t ws_size,
                              hipStream_t stream) {
  (void)in_sizes; (void)n_in; (void)out_size;
  const float* x    = (const float*)d_in[0];
  const float* ge   = (const float*)d_in[1];
  const float* pemb = (const float*)d_in[2];
  const float* cb   = (const float*)d_in[3];
  const float* ecs  = (const float*)d_in[4];
  const float* ad   = (const float*)d_in[5];
  const float* sd   = (const float*)d_in[6];
  const float* bd   = (const float*)d_in[7];
  const float* au   = (const float*)d_in[8];
  const float* su   = (const float*)d_in[9];
  const float* bu   = (const float*)d_in[10];

  float* out0  = (float*)d_out;                         // [N, CIN]; doubles as pc scratch
  float* outL  = out0 + (size_t)NROWS * CIN;            // scalar c_loss
  float* outCB = outL + 1;                              // [K, CIN]
  float* outE  = outCB + (size_t)KCB * CIN;             // [K]

  // workspace layout
  char* w = (char*)d_ws;
  float*  wdT  = (float*) (w + 0);         //    65,536
  float*  wuT  = (float*) (w + 65536);     //    65,536
  float*  cb2  = (float*) (w + 131072);    //     8,192
  ushort* cbth = (ushort*)(w + 139264);    // 1,048,576  tiled bf16 hi
  ushort* cbtl = (ushort*)(w + 1187840);   // 1,048,576  tiled bf16 lo
  int*    dr   = (int*)   (w + 2236416);   // 1,310,720  draws [10][N]
  int*    cnt  = (int*)   (w + 3547136);   //     8,192
  int*    off  = (int*)   (w + 3555328);   //     8,192
  int*    cur  = (int*)   (w + 3563520);   //     8,192
  float*  clo  = (float*) (w + 3571712);   //       256
  float*  dwa  = (float*) (w + 3571968);   // 2,097,152  dw accum [K][CIN]
  float*  emaw = (float*) (w + 5669120);   //     8,192
  int*    rows = (int*)   (w + 5677312);   // 1,310,720  rows_sorted
  int*    keys = (int*)   (w + 6988032);   // 1,310,720  keys_sorted
  const size_t NEED_SORT = 8298752u;
  bool use_sort = ws_size >= NEED_SORT;

  // zero cnt+off+cur+clo+dwa (contiguous)
  hipMemsetAsync(cnt, 0, 5669120 - 3547136, stream);

  k_weights<<<128, 256, 0, stream>>>(ad, sd, au, su, wdT, wuT);
  k_cbprep<<<KCB, 256, 0, stream>>>(cb, cb2, cbth, cbtl);
  k_pcf<<<NROWS, 256, 0, stream>>>(ge, wdT, bd, wuT, bu, out0);      // pc -> out0 region
  k_sample<<<NROWS / 32, 256, 0, stream>>>(out0, cbth, cbtl, cb2, dr);
  k_hist<<<64, 256, 0, stream>>>(dr, cnt);
  if (use_sort) {
    k_scan<<<1, 256, 0, stream>>>(cnt, off, cur);
    k_scatter<<<64, 256, 0, stream>>>(dr, cur, rows, keys);
    k_dwgather<<<(NSAMP * NROWS) / 128, 256, 0, stream>>>(rows, keys, out0, dwa);
  } else {
    k_dw<<<NROWS, 256, 0, stream>>>(dr, out0, dwa);
  }
  k_ema<<<1, 256, 0, stream>>>(cnt, ecs, outE, emaw);
  k_out0<<<NROWS, 256, 0, stream>>>(dr, cb, out0, x, pemb, clo);     // in-place transform
  k_final<<<1, 64, 0, stream>>>(clo, outL);
  k_codebook<<<2048, 256, 0, stream>>>(dwa, cb, emaw, outCB);
}

// Round 7
// 527.865 us; speedup vs baseline: 15.8100x; 1.9272x over previous
//
#include <hip/hip_runtime.h>
#include <cstdint>
#include <cstddef>

// Problem constants
#define NROWS 32768
#define CIN 256
#define CHID 64
#define KCB 2048
#define NSAMP 10

constexpr uint32_t NKu   = 67108864u;   // NROWS*KCB
constexpr uint32_t HALFu = 335544320u;  // 5*NKu (counter offset for second word's draw)

using f32x4 = __attribute__((ext_vector_type(4))) float;
using bf16x8 = __attribute__((ext_vector_type(8))) short;

// ---------------- threefry2x32 (key = jax.random.key(42) -> (0,42)) ----------------
__device__ __forceinline__ void tf2x32(uint32_t x0, uint32_t x1,
                                       uint32_t& o0, uint32_t& o1) {
  constexpr uint32_t K0c = 0u, K1c = 42u;
  constexpr uint32_t K2c = 0x1BD11BDAu ^ K0c ^ K1c;
  const uint32_t ks[3] = {K0c, K1c, K2c};
  x0 += K0c; x1 += K1c;
#pragma unroll
  for (int g = 0; g < 5; ++g) {
    const int R0 = (g & 1) ? 17 : 13;
    const int R1 = (g & 1) ? 29 : 15;
    const int R2 = (g & 1) ? 16 : 26;
    const int R3 = (g & 1) ? 24 : 6;
    x0 += x1; x1 = (x1 << R0) | (x1 >> (32 - R0)); x1 ^= x0;
    x0 += x1; x1 = (x1 << R1) | (x1 >> (32 - R1)); x1 ^= x0;
    x0 += x1; x1 = (x1 << R2) | (x1 >> (32 - R2)); x1 ^= x0;
    x0 += x1; x1 = (x1 << R3) | (x1 >> (32 - R3)); x1 ^= x0;
    x0 += ks[(g + 1) % 3];
    x1 += ks[(g + 2) % 3] + (uint32_t)(g + 1);
  }
  o0 = x0; o1 = x1;
}

__device__ __forceinline__ ushort bf16_rne(float x) {
  uint32_t b = __float_as_uint(x);
  return (ushort)((b + 0x7fffu + ((b >> 16) & 1u)) >> 16);
}
__device__ __forceinline__ float bf16_tof(ushort u) {
  return __uint_as_float(((uint32_t)u) << 16);
}

// float <-> order-preserving uint (for atomicMin/Max races on signed floats)
__device__ __forceinline__ uint32_t fenc(float f) {
  uint32_t u = __float_as_uint(f);
  return (u & 0x80000000u) ? ~u : (u | 0x80000000u);
}
__device__ __forceinline__ float fdec(uint32_t e) {
  uint32_t u = (e & 0x80000000u) ? (e ^ 0x80000000u) : ~e;
  return __uint_as_float(u);
}

// ---------------- PHM weights -> lane-tiled bf16 hi/lo fragments ----------------
// down dest: ((jt*8 + ks)*64 + lane)*8 + e  <-> W_down[jt*16 + (lane&15)][ks*32 + 8*(lane>>4) + e]
// up   dest: ((cot*2 + ks2)*64 + lane)*8 + e <-> W_up[cot*16 + (lane&15)][ks2*32 + 8*(lane>>4) + e]
__global__ void __launch_bounds__(256) k_weights(
    const float* __restrict__ ad, const float* __restrict__ sd,
    const float* __restrict__ au, const float* __restrict__ su,
    ushort* __restrict__ wdh, ushort* __restrict__ wdl,
    ushort* __restrict__ wuh, ushort* __restrict__ wul) {
  int gid = blockIdx.x * 256 + threadIdx.x;
  if (gid < CHID * CIN) {            // W_down [64][256]
    int r = gid >> 8, c = gid & 255;
    int i = r >> 4, kq = r & 15, j = c >> 6, l = c & 63;
    float acc = 0.f;
#pragma unroll
    for (int n = 0; n < 4; ++n)
      acc = fmaf(ad[n * 16 + i * 4 + j], sd[n * 1024 + kq * 64 + l], acc);
    int jt = r >> 4, l15 = r & 15, ks = c >> 5, lq = (c >> 3) & 3, e = c & 7;
    size_t di = (size_t)(((jt * 8 + ks) * 64) + lq * 16 + l15) * 8 + e;
    ushort hi = bf16_rne(acc);
    wdh[di] = hi;
    wdl[di] = bf16_rne(acc - bf16_tof(hi));
  } else {                           // W_up [256][64]
    int g2 = gid - CHID * CIN;
    int r = g2 >> 6, c = g2 & 63;
    int i = r >> 6, kq = r & 63, j = c >> 4, l = c & 15;
    float acc = 0.f;
#pragma unroll
    for (int n = 0; n < 4; ++n)
      acc = fmaf(au[n * 16 + i * 4 + j], su[n * 1024 + kq * 16 + l], acc);
    int cot = r >> 4, l15 = r & 15, ks2 = c >> 5, lq = (c >> 3) & 3, e = c & 7;
    size_t di = (size_t)(((cot * 2 + ks2) * 64) + lq * 16 + l15) * 8 + e;
    ushort hi = bf16_rne(acc);
    wuh[di] = hi;
    wul[di] = bf16_rne(acc - bf16_tof(hi));
  }
}

// cb prep: row norms + lane-tiled bf16 hi/lo layout for coalesced MFMA A-frags.
__global__ void __launch_bounds__(256) k_cbprep(
    const float* __restrict__ cb, float* __restrict__ cb2,
    ushort* __restrict__ th, ushort* __restrict__ tl) {
  __shared__ float wsum[4];
  int k = blockIdx.x, c = threadIdx.x;
  float v = cb[(size_t)k * CIN + c];
  float sq = v * v;
#pragma unroll
  for (int m = 1; m < 64; m <<= 1) sq += __shfl_xor(sq, m, 64);
  if ((c & 63) == 0) wsum[c >> 6] = sq;
  __syncthreads();
  if (c == 0) cb2[k] = wsum[0] + wsum[1] + wsum[2] + wsum[3];
  ushort hi = bf16_rne(v);
  ushort lo = bf16_rne(v - bf16_tof(hi));
  int t = k >> 5, r5 = k & 31, kh = r5 >> 4, l15 = r5 & 15;
  int ks = c >> 5, c5 = c & 31, lq = c5 >> 3, e = c5 & 7;
  size_t di = (size_t)((((t * 2 + kh) * 8 + ks) * 64) + lq * 16 + l15) * 8 + e;
  th[di] = hi; tl[di] = lo;
}

// ---------------- MFMA PHM: pc = relu(ge@Wd^T+bd)@Wu^T+bu, 32 rows/block ----------------
__global__ void __launch_bounds__(256, 2) k_pcf2(
    const float* __restrict__ ge, const ushort* __restrict__ wdh,
    const ushort* __restrict__ wdl, const float* __restrict__ bd,
    const ushort* __restrict__ wuh, const ushort* __restrict__ wul,
    const float* __restrict__ bu, float* __restrict__ pc) {
  __shared__ float hlds[32][68];
  int tid = threadIdx.x, w = tid >> 6, lane = tid & 63;
  int l15 = lane & 15, lq = lane >> 4;

  // ge fragments (bf16 hi), rows l15 and l15+16
  bf16x8 geh[2][8];
#pragma unroll
  for (int ih = 0; ih < 2; ++ih) {
    const float* grow = ge + (size_t)(blockIdx.x * 32 + ih * 16 + l15) * CIN;
#pragma unroll
    for (int ks = 0; ks < 8; ++ks) {
      float4 a = *(const float4*)(grow + ks * 32 + 8 * lq);
      float4 b = *(const float4*)(grow + ks * 32 + 8 * lq + 4);
      float vv[8] = {a.x, a.y, a.z, a.w, b.x, b.y, b.z, b.w};
#pragma unroll
      for (int e = 0; e < 8; ++e) geh[ih][ks][e] = (short)bf16_rne(vv[e]);
    }
  }

  // down-proj: wave w owns j-tile jt = w
#pragma unroll
  for (int ih = 0; ih < 2; ++ih) {
    f32x4 acc = {0.f, 0.f, 0.f, 0.f};
#pragma unroll
    for (int ks = 0; ks < 8; ++ks) {
      bf16x8 ah = *(const bf16x8*)(wdh + ((size_t)(w * 8 + ks) * 64 + lane) * 8);
      bf16x8 al = *(const bf16x8*)(wdl + ((size_t)(w * 8 + ks) * 64 + lane) * 8);
      acc = __builtin_amdgcn_mfma_f32_16x16x32_bf16(ah, geh[ih][ks], acc, 0, 0, 0);
      acc = __builtin_amdgcn_mfma_f32_16x16x32_bf16(al, geh[ih][ks], acc, 0, 0, 0);
    }
    float4 bd4 = *(const float4*)(bd + w * 16 + 4 * lq);
    float4 hv;
    hv.x = fmaxf(acc[0] + bd4.x, 0.f);
    hv.y = fmaxf(acc[1] + bd4.y, 0.f);
    hv.z = fmaxf(acc[2] + bd4.z, 0.f);
    hv.w = fmaxf(acc[3] + bd4.w, 0.f);
    *(float4*)&hlds[ih * 16 + l15][w * 16 + 4 * lq] = hv;
  }
  __syncthreads();

  // h fragments (bf16 hi)
  bf16x8 hh[2][2];
#pragma unroll
  for (int ih = 0; ih < 2; ++ih)
#pragma unroll
    for (int ks2 = 0; ks2 < 2; ++ks2) {
      float4 a = *(const float4*)&hlds[ih * 16 + l15][ks2 * 32 + 8 * lq];
      float4 b = *(const float4*)&hlds[ih * 16 + l15][ks2 * 32 + 8 * lq + 4];
      float vv[8] = {a.x, a.y, a.z, a.w, b.x, b.y, b.z, b.w};
#pragma unroll
      for (int e = 0; e < 8; ++e) hh[ih][ks2][e] = (short)bf16_rne(vv[e]);
    }

  // up-proj: wave w owns co-tiles w*4 .. w*4+3
#pragma unroll
  for (int ct = 0; ct < 4; ++ct) {
    int cot = w * 4 + ct;
#pragma unroll
    for (int ih = 0; ih < 2; ++ih) {
      f32x4 acc = {0.f, 0.f, 0.f, 0.f};
#pragma unroll
      for (int ks2 = 0; ks2 < 2; ++ks2) {
        bf16x8 ah = *(const bf16x8*)(wuh + ((size_t)(cot * 2 + ks2) * 64 + lane) * 8);
        bf16x8 al = *(const bf16x8*)(wul + ((size_t)(cot * 2 + ks2) * 64 + lane) * 8);
        acc = __builtin_amdgcn_mfma_f32_16x16x32_bf16(ah, hh[ih][ks2], acc, 0, 0, 0);
        acc = __builtin_amdgcn_mfma_f32_16x16x32_bf16(al, hh[ih][ks2], acc, 0, 0, 0);
      }
      int co0 = cot * 16 + 4 * lq;
      float4 bu4 = *(const float4*)(bu + co0);
      float4 o;
      o.x = acc[0] + bu4.x; o.y = acc[1] + bu4.y;
      o.z = acc[2] + bu4.z; o.w = acc[3] + bu4.w;
      int i_abs = blockIdx.x * 32 + ih * 16 + l15;
      *(float4*)(pc + (size_t)i_abs * CIN + co0) = o;
    }
  }
}

// ---------------- drain helper: exact threefry + log-race ----------------
__device__ __forceinline__ void drain_q(
    const unsigned long long* qw, int n, int lane, uint32_t i0k,
    unsigned long long (*bests)[NSAMP]) {
  for (int j = lane; j < n; j += 64) {
    unsigned long long e = qw[j];
    float score = __uint_as_float((uint32_t)(e >> 32));
    int il = (int)((e >> 11) & 31u);
    int k  = (int)(e & 2047u);
    uint32_t kb = i0k + (uint32_t)il * KCB + (uint32_t)k;
#pragma unroll
    for (int s5 = 0; s5 < 5; ++s5) {
      uint32_t blk = (uint32_t)s5 * NKu + kb;
      uint32_t o0, o1;
      tf2x32(blk, blk + HALFu, o0, o1);
      float u0 = __uint_as_float((o0 >> 9) | 0x3f800000u) - 1.0f;
      float u1 = __uint_as_float((o1 >> 9) | 0x3f800000u) - 1.0f;
      float E0 = -__logf(fmaxf(u0, 1.17549435e-38f));
      float E1 = -__logf(fmaxf(u1, 1.17549435e-38f));
      float v0 = __logf(E0) - score;
      float v1 = __logf(E1) - score;
      unsigned long long p0 = (((unsigned long long)fenc(v0)) << 32) | (uint32_t)k;
      unsigned long long p1 = (((unsigned long long)fenc(v1)) << 32) | (uint32_t)k;
      atomicMin(&bests[il][s5], p0);
      atomicMin(&bests[il][s5 + 5], p1);
    }
  }
}

// ---------------- Single-pass pruned MFMA sampler ----------------
__global__ void __launch_bounds__(256, 3) k_sample(
    const float* __restrict__ pc, const ushort* __restrict__ th,
    const ushort* __restrict__ tl, const float* __restrict__ cb2,
    int* __restrict__ draws) {
  __shared__ unsigned long long bests[32][NSAMP];
  __shared__ unsigned long long q[4][128];
  __shared__ uint32_t menc[32];
  __shared__ float bias2[KCB];

  int tid = threadIdx.x;
  int w = tid >> 6, lane = tid & 63;
  int ih = w & 1, kh = w >> 1;
  int l15 = lane & 15, lq = lane >> 4;

  for (int e = tid; e < 32 * NSAMP; e += 256)
    ((unsigned long long*)bests)[e] = ~0ull;
  if (tid < 32) menc[tid] = 0u;
  for (int kk = tid; kk < KCB; kk += 256) bias2[kk] = -0.5f * cb2[kk];

  int i_loc = l15 + 16 * ih;
  int i_abs = blockIdx.x * 32 + i_loc;

  bf16x8 pch[8], pcl[8];
  {
    const float* prow = pc + (size_t)i_abs * CIN;
#pragma unroll
    for (int ks = 0; ks < 8; ++ks) {
      float4 a = *(const float4*)(prow + ks * 32 + 8 * lq);
      float4 b = *(const float4*)(prow + ks * 32 + 8 * lq + 4);
      float vv[8] = {a.x, a.y, a.z, a.w, b.x, b.y, b.z, b.w};
#pragma unroll
      for (int e = 0; e < 8; ++e) {
        ushort hi = bf16_rne(vv[e]);
        pch[ks][e] = (short)hi;
        pcl[ks][e] = (short)bf16_rne(vv[e] - bf16_tof(hi));
      }
    }
  }
  __syncthreads();

  uint32_t i0k = (uint32_t)(blockIdx.x * 32) * (uint32_t)KCB;
  int qtail = 0;
  unsigned long long lmask = (1ull << lane) - 1ull;

  for (int t = 0; t < 64; ++t) {
    const ushort* ph = th + (size_t)((t * 2 + kh) * 8) * 512 + lane * 8;
    const ushort* pl = tl + (size_t)((t * 2 + kh) * 8) * 512 + lane * 8;
    int k0 = t * 32 + 16 * kh + 4 * lq;
    f32x4 acc = *(const f32x4*)&bias2[k0];
#pragma unroll
    for (int ks = 0; ks < 8; ++ks) {
      bf16x8 ah = *(const bf16x8*)(ph + ks * 512);
      bf16x8 al = *(const bf16x8*)(pl + ks * 512);
      acc = __builtin_amdgcn_mfma_f32_16x16x32_bf16(ah, pch[ks], acc, 0, 0, 0);
      acc = __builtin_amdgcn_mfma_f32_16x16x32_bf16(al, pch[ks], acc, 0, 0, 0);
      acc = __builtin_amdgcn_mfma_f32_16x16x32_bf16(ah, pcl[ks], acc, 0, 0, 0);
    }
    float sc[4];
#pragma unroll
    for (int r = 0; r < 4; ++r) sc[r] = 2.0f * acc[r];

    float mx = fmaxf(fmaxf(sc[0], sc[1]), fmaxf(sc[2], sc[3]));
    mx = fmaxf(mx, __shfl_xor(mx, 16, 64));
    mx = fmaxf(mx, __shfl_xor(mx, 32, 64));
    if (lane < 16) atomicMax(&menc[i_loc], fenc(mx));
    float thr = fdec(menc[i_loc]) - 18.0f;

#pragma unroll
    for (int r = 0; r < 4; ++r) {
      bool pass = sc[r] > thr;
      unsigned long long mask = __ballot(pass);
      if (pass) {
        int off = __popcll(mask & lmask);
        q[w][qtail + off] =
            (((unsigned long long)__float_as_uint(sc[r])) << 32) |
            ((unsigned long long)(uint32_t)i_loc << 11) |
            (unsigned long long)(uint32_t)(k0 + r);
      }
      qtail += (int)__popcll(mask);
      if (qtail >= 64) { drain_q(q[w], qtail, lane, i0k, bests); qtail = 0; }
    }
  }
  drain_q(q[w], qtail, lane, i0k, bests);
  __syncthreads();
  for (int item = tid; item < 32 * NSAMP; item += 256) {
    int il = item / NSAMP, s = item % NSAMP;
    draws[s * NROWS + blockIdx.x * 32 + il] =
        (int)((uint32_t)(bests[il][s] & 0xFFFFFFFFull) & 2047u);
  }
}

// static sorting network (compile-time indices -> registers)
__device__ __forceinline__ void load_sorted_draws(const int* dl, int* d) {
#pragma unroll
  for (int s = 0; s < NSAMP; ++s) d[s] = dl[s];
#pragma unroll
  for (int p = 0; p < NSAMP - 1; ++p)
#pragma unroll
    for (int a = 0; a < NSAMP - 1 - p; ++a) {
      int lo = min(d[a], d[a + 1]);
      int hi = max(d[a], d[a + 1]);
      d[a] = lo; d[a + 1] = hi;
    }
}

// fallback dw (atomic-per-row) if workspace too small for sort path
__global__ void __launch_bounds__(256) k_dw(const int* __restrict__ draws,
                                            const float* __restrict__ pc,
                                            float* __restrict__ dw) {
  __shared__ int dl[NSAMP];
  int i = blockIdx.x, tid = threadIdx.x;
  if (tid < NSAMP) dl[tid] = draws[tid * NROWS + i];
  __syncthreads();
  int d[NSAMP];
  load_sorted_draws(dl, d);
  float pcv = pc[(size_t)i * CIN + tid];
#pragma unroll
  for (int a = 0; a < NSAMP; ++a) {
    bool first = (a == 0) || (d[a] != d[a - 1]);
    if (first) {
      int c = 1;
#pragma unroll
      for (int b2 = a + 1; b2 < NSAMP; ++b2) c += (d[b2] == d[a]) ? 1 : 0;
      atomicAdd(&dw[(size_t)d[a] * CIN + tid], (float)c * pcv);
    }
  }
}

// per-k draw counts via LDS histogram
__global__ void __launch_bounds__(256) k_hist(const int* __restrict__ draws,
                                              int* __restrict__ counts) {
  __shared__ int hist[KCB];
  for (int b = threadIdx.x; b < KCB; b += 256) hist[b] = 0;
  __syncthreads();
  const int total = NSAMP * NROWS;
  for (int idx = blockIdx.x * 256 + threadIdx.x; idx < total; idx += gridDim.x * 256)
    atomicAdd(&hist[draws[idx]], 1);
  __syncthreads();
  for (int b = threadIdx.x; b < KCB; b += 256)
    if (hist[b]) atomicAdd(&counts[b], hist[b]);
}

// exclusive scan of counts -> off, cur
__global__ void k_scan(const int* __restrict__ cnt, int* __restrict__ off,
                       int* __restrict__ cur) {
  __shared__ int part[256];
  __shared__ int pref[256];
  int tid = threadIdx.x;
  int loc[8];
  int s = 0;
  int base = tid * 8;
#pragma unroll
  for (int j = 0; j < 8; ++j) { loc[j] = cnt[base + j]; s += loc[j]; }
  part[tid] = s;
  __syncthreads();
  if (tid == 0) {
    int a = 0;
    for (int i2 = 0; i2 < 256; ++i2) { pref[i2] = a; a += part[i2]; }
  }
  __syncthreads();
  int a = pref[tid];
#pragma unroll
  for (int j = 0; j < 8; ++j) { off[base + j] = a; cur[base + j] = a; a += loc[j]; }
}

// counting-sort scatter: draws -> (rows_sorted, keys_sorted) grouped by k
__global__ void __launch_bounds__(256) k_scatter(const int* __restrict__ dr,
                                                 int* __restrict__ cur,
                                                 int* __restrict__ rows,
                                                 int* __restrict__ keys) {
  __shared__ int h[KCB];
  __shared__ int basek[KCB];
  int tid = threadIdx.x;
  for (int k = tid; k < KCB; k += 256) h[k] = 0;
  __syncthreads();
  int f0 = blockIdx.x * 5120;
  for (int j = tid; j < 5120; j += 256) atomicAdd(&h[dr[f0 + j]], 1);
  __syncthreads();
  for (int k = tid; k < KCB; k += 256) {
    int hv = h[k];
    basek[k] = hv ? atomicAdd(&cur[k], hv) : 0;
    h[k] = 0;
  }
  __syncthreads();
  for (int j = tid; j < 5120; j += 256) {
    int k = dr[f0 + j];
    int li = atomicAdd(&h[k], 1);
    int pos = basek[k] + li;
    rows[pos] = (f0 + j) & (NROWS - 1);
    keys[pos] = k;
  }
}

// segment gather: dw[k] += sum of pc rows (128 entries/block, 1 flush per k-run)
__global__ void __launch_bounds__(256) k_dwgather(const int* __restrict__ rows,
                                                  const int* __restrict__ keys,
                                                  const float* __restrict__ pc,
                                                  float* __restrict__ dw) {
  __shared__ int kk[128];
  __shared__ int rr[128];
  int tid = threadIdx.x;
  int j0 = blockIdx.x * 128;
  if (tid < 128) { kk[tid] = keys[j0 + tid]; rr[tid] = rows[j0 + tid]; }
  __syncthreads();
  int c = tid;
  float acc = 0.f;
  int kprev = kk[0];
  for (int j = 0; j < 128; ++j) {
    int k = kk[j];
    if (k != kprev) {
      atomicAdd(&dw[(size_t)kprev * CIN + c], acc);
      acc = 0.f; kprev = k;
    }
    acc += pc[(size_t)rr[j] * CIN + c];
  }
  atomicAdd(&dw[(size_t)kprev * CIN + c], acc);
}

// out0 = x + (p_c + (p_q - p_c)) + p_emb, 16 rows/block, float4, 1 atomic/block
__global__ void __launch_bounds__(256) k_out0(
    const int* __restrict__ draws, const float* __restrict__ cb,
    float* __restrict__ pc_out0, const float* __restrict__ x,
    const float* __restrict__ pemb, float* __restrict__ closs) {
  __shared__ int dl[4][NSAMP];
  __shared__ float red[4];
  int tid = threadIdx.x;
  int w = tid >> 6, lane = tid & 63;
  int rsub = tid >> 6;
  int c4 = (tid & 63) * 4;
  float4 pe = *(const float4*)(pemb + c4);
  float lacc = 0.f;
#pragma unroll
  for (int it = 0; it < 4; ++it) {
    int i0 = blockIdx.x * 16 + it * 4;
    __syncthreads();
    if (tid < 40) {
      int r = tid / 10, s = tid - r * 10;
      dl[r][s] = draws[s * NROWS + i0 + r];
    }
    __syncthreads();
    int d[NSAMP];
    load_sorted_draws(dl[rsub], d);
    int i = i0 + rsub;
    float4 acc = {0.f, 0.f, 0.f, 0.f};
#pragma unroll
    for (int a = 0; a < NSAMP; ++a) {
      bool first = (a == 0) || (d[a] != d[a - 1]);
      if (first) {
        int cct = 1;
#pragma unroll
        for (int b2 = a + 1; b2 < NSAMP; ++b2) cct += (d[b2] == d[a]) ? 1 : 0;
        float cf = (float)cct;
        float4 cv = *(const float4*)(cb + (size_t)d[a] * CIN + c4);
        acc.x = fmaf(cf, cv.x, acc.x);
        acc.y = fmaf(cf, cv.y, acc.y);
        acc.z = fmaf(cf, cv.z, acc.z);
        acc.w = fmaf(cf, cv.w, acc.w);
      }
    }
    float4 pcv = *(const float4*)(pc_out0 + (size_t)i * CIN + c4);
    float4 xv  = *(const float4*)(x + (size_t)i * CIN + c4);
    float4 pq, t, o;
    pq.x = acc.x * 0.1f; pq.y = acc.y * 0.1f; pq.z = acc.z * 0.1f; pq.w = acc.w * 0.1f;
    t.x = pq.x - pcv.x; t.y = pq.y - pcv.y; t.z = pq.z - pcv.z; t.w = pq.w - pcv.w;
    o.x = xv.x + ((pcv.x + t.x) + pe.x);
    o.y = xv.y + ((pcv.y + t.y) + pe.y);
    o.z = xv.z + ((pcv.z + t.z) + pe.z);
    o.w = xv.w + ((pcv.w + t.w) + pe.w);
    *(float4*)(pc_out0 + (size_t)i * CIN + c4) = o;
    lacc += t.x * t.x + t.y * t.y + t.z * t.z + t.w * t.w;
  }
#pragma unroll
  for (int m = 1; m < 64; m <<= 1) lacc += __shfl_xor(lacc, m, 64);
  if (lane == 0) red[w] = lacc;
  __syncthreads();
  if (tid == 0) atomicAdd(closs, red[0] + red[1] + red[2] + red[3]);
}

__global__ void k_final(const float* __restrict__ closs, float* __restrict__ dst) {
  if (blockIdx.x == 0 && threadIdx.x == 0) dst[0] = closs[0] / 8388608.0f;
}

// EMA cluster-size update (single block for deterministic n_tot)
__global__ void __launch_bounds__(256) k_ema(
    const int* __restrict__ counts, const float* __restrict__ ecs,
    float* __restrict__ ema_dst, float* __restrict__ ema_ws) {
  __shared__ float e_sh[KCB];
  __shared__ float red[256];
  int tid = threadIdx.x;
  float psum = 0.f;
  for (int k = tid; k < KCB; k += 256) {
    float s10 = (float)counts[k] / 10.0f;
    float e = ecs[k] * 0.9f + 0.1f * s10;
    e_sh[k] = e;
    psum += e;
  }
  red[tid] = psum;
  __syncthreads();
  for (int off = 128; off > 0; off >>= 1) {
    if (tid < off) red[tid] += red[tid + off];
    __syncthreads();
  }
  float ntot = red[0];
  float denom = ntot + 20.48f;   // K * EPS
  for (int k = tid; k < KCB; k += 256) {
    float v = (e_sh[k] + 0.01f) / denom * ntot;
    ema_dst[k] = v;
    ema_ws[k]  = v;
  }
}

// new_codebook = cb*0.9 + 0.1*((dw/10) / ema)
__global__ void k_codebook(const float* __restrict__ dw,
                           const float* __restrict__ cb,
                           const float* __restrict__ ema_ws,
                           float* __restrict__ out_cb) {
  int gid = blockIdx.x * blockDim.x + threadIdx.x;
  if (gid >= KCB * CIN) return;
  int k = gid >> 8;
  float dw10 = dw[gid] / 10.0f;
  float ratio = dw10 / ema_ws[k];
  out_cb[gid] = cb[gid] * 0.9f + 0.1f * ratio;
}

extern "C" void kernel_launch(void* const* d_in, const int* in_sizes, int n_in,
                              void* d_out, int out_size, void* d_ws, size_t ws_size,
                              hipStream_t stream) {
  (void)in_sizes; (void)n_in; (void)out_size;
  const float* x    = (const float*)d_in[0];
  const float* ge   = (const float*)d_in[1];
  const float* pemb = (const float*)d_in[2];
  const float* cb   = (const float*)d_in[3];
  const float* ecs  = (const float*)d_in[4];
  const float* ad   = (const float*)d_in[5];
  const float* sd   = (const float*)d_in[6];
  const float* bd   = (const float*)d_in[7];
  const float* au   = (const float*)d_in[8];
  const float* su   = (const float*)d_in[9];
  const float* bu   = (const float*)d_in[10];

  float* out0  = (float*)d_out;                         // [N, CIN]; doubles as pc scratch
  float* outL  = out0 + (size_t)NROWS * CIN;            // scalar c_loss
  float* outCB = outL + 1;                              // [K, CIN]
  float* outE  = outCB + (size_t)KCB * CIN;             // [K]

  // workspace layout
  char* w = (char*)d_ws;
  ushort* wdh  = (ushort*)(w + 0);         //    32,768  W_down tiled bf16 hi
  ushort* wdl  = (ushort*)(w + 32768);     //    32,768  W_down tiled bf16 lo
  ushort* wuh  = (ushort*)(w + 65536);     //    32,768  W_up tiled bf16 hi
  ushort* wul  = (ushort*)(w + 98304);     //    32,768  W_up tiled bf16 lo
  float*  cb2  = (float*) (w + 131072);    //     8,192
  ushort* cbth = (ushort*)(w + 139264);    // 1,048,576  cb tiled bf16 hi
  ushort* cbtl = (ushort*)(w + 1187840);   // 1,048,576  cb tiled bf16 lo
  int*    dr   = (int*)   (w + 2236416);   // 1,310,720  draws [10][N]
  int*    cnt  = (int*)   (w + 3547136);   //     8,192
  int*    off  = (int*)   (w + 3555328);   //     8,192
  int*    cur  = (int*)   (w + 3563520);   //     8,192
  float*  clo  = (float*) (w + 3571712);   //       256
  float*  dwa  = (float*) (w + 3571968);   // 2,097,152  dw accum [K][CIN]
  float*  emaw = (float*) (w + 5669120);   //     8,192
  int*    rows = (int*)   (w + 5677312);   // 1,310,720  rows_sorted
  int*    keys = (int*)   (w + 6988032);   // 1,310,720  keys_sorted
  const size_t NEED_SORT = 8298752u;
  bool use_sort = ws_size >= NEED_SORT;

  // zero cnt+off+cur+clo+dwa (contiguous)
  hipMemsetAsync(cnt, 0, 5669120 - 3547136, stream);

  k_weights<<<128, 256, 0, stream>>>(ad, sd, au, su, wdh, wdl, wuh, wul);
  k_cbprep<<<KCB, 256, 0, stream>>>(cb, cb2, cbth, cbtl);
  k_pcf2<<<NROWS / 32, 256, 0, stream>>>(ge, wdh, wdl, bd, wuh, wul, bu, out0);
  k_sample<<<NROWS / 32, 256, 0, stream>>>(out0, cbth, cbtl, cb2, dr);
  k_hist<<<64, 256, 0, stream>>>(dr, cnt);
  if (use_sort) {
    k_scan<<<1, 256, 0, stream>>>(cnt, off, cur);
    k_scatter<<<64, 256, 0, stream>>>(dr, cur, rows, keys);
    k_dwgather<<<(NSAMP * NROWS) / 128, 256, 0, stream>>>(rows, keys, out0, dwa);
  } else {
    k_dw<<<NROWS, 256, 0, stream>>>(dr, out0, dwa);
  }
  k_ema<<<1, 256, 0, stream>>>(cnt, ecs, outE, emaw);
  k_out0<<<NROWS / 16, 256, 0, stream>>>(dr, cb, out0, x, pemb, clo);
  k_final<<<1, 64, 0, stream>>>(clo, outL);
  k_codebook<<<2048, 256, 0, stream>>>(dwa, cb, emaw, outCB);
}